// Round 3
// baseline (398.570 us; speedup 1.0000x reference)
//
#include <hip/hip_runtime.h>
#include <hip/hip_bf16.h>
#include <math.h>

#define T_   4096
#define B_   4
#define C_   256
#define C3_  768
#define H_   1024
#define E_   4
#define M_   (B_*T_)      // 16384 rows
#define NCH_ 64
#define CHL_ (T_/NCH_)    // 64
#define KH_  4096         // E*H

typedef __attribute__((ext_vector_type(8))) short short8;
typedef __attribute__((ext_vector_type(4))) float floatx4;

__device__ __forceinline__ float b2f(unsigned short u) {
  union { unsigned int i; float f; } x; x.i = ((unsigned int)u) << 16; return x.f;
}
__device__ __forceinline__ unsigned short f2b(float f) {
  __hip_bfloat16 h = __float2bfloat16(f);
  return *reinterpret_cast<unsigned short*>(&h);
}
__device__ __forceinline__ void unpack8(uint4 a, float* f) {
  unsigned int w[4] = {a.x, a.y, a.z, a.w};
  #pragma unroll
  for (int i = 0; i < 4; i++) {
    union { unsigned int u; float g; } lo, hi;
    lo.u = w[i] << 16; hi.u = w[i] & 0xffff0000u;
    f[2*i] = lo.g; f[2*i+1] = hi.g;
  }
}
__device__ __forceinline__ void gl_lds16(const void* g, void* l) {
  __builtin_amdgcn_global_load_lds(
      (const __attribute__((address_space(1))) void*)g,
      (__attribute__((address_space(3))) void*)l, 16, 0, 0);
}
// sigmoid GELU: x*sigma(1.702x). |err|<=~0.01 on hid; attenuated by zero-mean w2 down-sum.
// Numerics verified on HW: passed with absmax 0.03125 using this form.
__device__ __forceinline__ float gelu_s(float v) {
  float e = __expf(-1.702f * v);
  return v * __builtin_amdgcn_rcpf(1.0f + e);
}
// pack 4 floats -> 4 fp8 e4m3 (OCP) in one uint
__device__ __forceinline__ unsigned int pk_fp8x4(float a, float b, float c, float d) {
  unsigned int v = 0;
  v = __builtin_amdgcn_cvt_pk_fp8_f32(a, b, v, false);
  v = __builtin_amdgcn_cvt_pk_fp8_f32(c, d, v, true);
  return v;
}
__device__ __forceinline__ unsigned char f2fp8(float v) {
  return (unsigned char)(__builtin_amdgcn_cvt_pk_fp8_f32(v, v, 0, false) & 0xff);
}
__device__ __forceinline__ float sel4(float4 v, int e) {
  float r = v.x;
  r = (e == 1) ? v.y : r;
  r = (e == 2) ? v.z : r;
  r = (e == 3) ? v.w : r;
  return r;
}

// ---------------- transpose + fp32->bf16: src[K,N](+z*K*N) -> dst[+z*zStr][n*dstLd + k] ----
__global__ __launch_bounds__(256) void transpose_cvt(
    const float* __restrict__ src, unsigned short* __restrict__ dst, int K, int N,
    int dstLd, size_t dstZStride) {
  __shared__ float tile[32][33];
  src += (size_t)blockIdx.z * K * N;
  dst += (size_t)blockIdx.z * dstZStride;
  int n0 = blockIdx.x * 32, k0 = blockIdx.y * 32;
  int tx = threadIdx.x, ty = threadIdx.y;   // blockDim (32,8)
  #pragma unroll
  for (int i = 0; i < 32; i += 8)
    tile[ty + i][tx] = src[(size_t)(k0 + ty + i) * N + n0 + tx];
  __syncthreads();
  #pragma unroll
  for (int i = 0; i < 32; i += 8)
    dst[(size_t)(n0 + ty + i) * dstLd + k0 + tx] = f2b(tile[tx][ty + i]);
}

// ---------------- w2 -> fp8 blocked: w2b[chunk=k>>6][c][64 bytes, seg-swizzled] ----------
// value = fp8(w2[e][h][c] * 256), k = e*1024+h.  Within the 64-byte row the 16B seg s
// is stored at s ^ ((c>>1)&3)  -> bank index injective in (c&7): 2-way (free) on the
// down-GEMM's b64 reads (the old s^(c&3) gave 4-way: bank ignored bit0 of c>>1).
__global__ __launch_bounds__(256) void transpose_w2_fp8(
    const float* __restrict__ src, unsigned char* __restrict__ dst) {
  __shared__ float tile[32][33];
  int e = blockIdx.z;
  src += (size_t)e * H_ * C_;
  int h0 = blockIdx.x * 32, c0 = blockIdx.y * 32;
  int tx = threadIdx.x, ty = threadIdx.y;
  #pragma unroll
  for (int i = 0; i < 32; i += 8)
    tile[ty + i][tx] = src[(size_t)(h0 + ty + i) * C_ + c0 + tx];
  __syncthreads();
  int k = e * H_ + h0 + tx;
  int chunk = k >> 6, kc = k & 63;
  #pragma unroll
  for (int i = 0; i < 32; i += 8) {
    int c = c0 + ty + i;
    int sw = ((((kc >> 4) ^ ((c >> 1) & 3)) << 4) | (kc & 15));
    dst[((size_t)chunk * 256 + c) * 64 + sw] = f2fp8(tile[tx][ty + i] * 256.0f);
  }
}

// ---------------- LayerNorm 1 ----------------
__global__ __launch_bounds__(256) void ln1_kernel(
    const float* __restrict__ x, const float* __restrict__ g,
    const float* __restrict__ b, unsigned short* __restrict__ h) {
  __shared__ float red[4];
  int row = blockIdx.x, tid = threadIdx.x;
  float v = x[(size_t)row * C_ + tid];
  float s = v;
  #pragma unroll
  for (int o = 32; o; o >>= 1) s += __shfl_xor(s, o);
  if ((tid & 63) == 0) red[tid >> 6] = s;
  __syncthreads();
  float mean = (red[0] + red[1] + red[2] + red[3]) * (1.0f / C_);
  __syncthreads();
  float d = v - mean;
  float q = d * d;
  #pragma unroll
  for (int o = 32; o; o >>= 1) q += __shfl_xor(q, o);
  if ((tid & 63) == 0) red[tid >> 6] = q;
  __syncthreads();
  float var = (red[0] + red[1] + red[2] + red[3]) * (1.0f / C_);
  h[(size_t)row * C_ + tid] = f2b(d * rsqrtf(var + 1e-5f) * g[tid] + b[tid]);
}

// ---------------- LayerNorm 2 + gating softmax (h2 bf16) ----------------
__global__ __launch_bounds__(256) void ln2_gates_kernel(
    const float* __restrict__ x1, const float* __restrict__ g,
    const float* __restrict__ b, const float* __restrict__ gw,
    const float* __restrict__ gb, unsigned short* __restrict__ h2,
    float* __restrict__ gates) {
  __shared__ float red[4];
  __shared__ float redg[4][4];
  int row = blockIdx.x, tid = threadIdx.x;
  float v = x1[(size_t)row * C_ + tid];
  float s = v;
  #pragma unroll
  for (int o = 32; o; o >>= 1) s += __shfl_xor(s, o);
  if ((tid & 63) == 0) red[tid >> 6] = s;
  __syncthreads();
  float mean = (red[0] + red[1] + red[2] + red[3]) * (1.0f / C_);
  __syncthreads();
  float d = v - mean;
  float q = d * d;
  #pragma unroll
  for (int o = 32; o; o >>= 1) q += __shfl_xor(q, o);
  if ((tid & 63) == 0) red[tid >> 6] = q;
  __syncthreads();
  float var = (red[0] + red[1] + red[2] + red[3]) * (1.0f / C_);
  float hv = d * rsqrtf(var + 1e-5f) * g[tid] + b[tid];
  h2[(size_t)row * C_ + tid] = f2b(hv);
  float p0 = hv * gw[tid * 4 + 0];
  float p1 = hv * gw[tid * 4 + 1];
  float p2 = hv * gw[tid * 4 + 2];
  float p3 = hv * gw[tid * 4 + 3];
  #pragma unroll
  for (int o = 32; o; o >>= 1) {
    p0 += __shfl_xor(p0, o); p1 += __shfl_xor(p1, o);
    p2 += __shfl_xor(p2, o); p3 += __shfl_xor(p3, o);
  }
  if ((tid & 63) == 0) {
    int w = tid >> 6;
    redg[w][0] = p0; redg[w][1] = p1; redg[w][2] = p2; redg[w][3] = p3;
  }
  __syncthreads();
  if (tid == 0) {
    float t4[4];
    #pragma unroll
    for (int e = 0; e < 4; e++)
      t4[e] = redg[0][e] + redg[1][e] + redg[2][e] + redg[3][e] + gb[e];
    float m = fmaxf(fmaxf(t4[0], t4[1]), fmaxf(t4[2], t4[3]));
    float zs = 0.f;
    #pragma unroll
    for (int e = 0; e < 4; e++) { t4[e] = __expf(t4[e] - m); zs += t4[e]; }
    float inv = 1.0f / zs;
    #pragma unroll
    for (int e = 0; e < 4; e++) gates[(size_t)row * 4 + e] = t4[e] * inv;
  }
}

// ---------------- chunked prefix scan of v ----------------
__global__ __launch_bounds__(256) void scan1_kernel(const unsigned short* __restrict__ qkv,
                                                    float* __restrict__ S) {
  int b = blockIdx.x >> 6, ch = blockIdx.x & 63, c = threadIdx.x;
  float s = 0.f;
  size_t base = ((size_t)b * T_ + (size_t)ch * CHL_) * C3_ + 512 + c;
  for (int t = 0; t < CHL_; t++) s += b2f(qkv[base + (size_t)t * C3_]);
  S[((size_t)b * NCH_ + ch) * C_ + c] = s;
}
__global__ __launch_bounds__(256) void scan2_kernel(float* __restrict__ S) {
  int b = blockIdx.x, c = threadIdx.x;
  float run = 0.f;
  for (int ch = 0; ch < NCH_; ch++) {
    size_t i = ((size_t)b * NCH_ + ch) * C_ + c;
    float t = S[i]; S[i] = run; run += t;
  }
}
__global__ __launch_bounds__(256) void scan3_kernel(const unsigned short* __restrict__ qkv,
                                                    const float* __restrict__ S,
                                                    unsigned short* __restrict__ Pb) {
  int b = blockIdx.x >> 6, ch = blockIdx.x & 63, c = threadIdx.x;
  float run = S[((size_t)b * NCH_ + ch) * C_ + c];
  size_t row0 = (size_t)b * T_ + (size_t)ch * CHL_;
  for (int t = 0; t < CHL_; t++) {
    run += b2f(qkv[(row0 + t) * C3_ + 512 + c]);
    Pb[(row0 + t) * C_ + c] = f2b(run);
  }
}

// ---------------- windowed attention: 16-lane group per window position ----------------
__global__ __launch_bounds__(256) void attn_kernel(
    const unsigned short* __restrict__ qkv, const unsigned short* __restrict__ Pb,
    const float* __restrict__ gate, unsigned short* __restrict__ aout) {
  int wave = threadIdx.x >> 6, lane = threadIdx.x & 63;
  int r = blockIdx.x * 4 + wave;
  int t = r & (T_ - 1);
  int g = lane >> 4, u = lane & 15;
  const unsigned short* qp = qkv + (size_t)r * C3_ + (u << 4);
  float qv[16];
  unpack8(*(const uint4*)qp, qv);
  unpack8(*(const uint4*)(qp + 8), qv + 8);
  float sc[5];
  #pragma unroll
  for (int rnd = 0; rnd < 5; rnd++) {
    int j = rnd * 4 + g;
    int jj = t - 16 + j;
    bool valid = (j <= 16) && (jj >= 0);
    float d = 0.f;
    if (valid) {
      const unsigned short* kp = qkv + (size_t)(r - 16 + j) * C3_ + 256 + (u << 4);
      float kv[16];
      unpack8(*(const uint4*)kp, kv);
      unpack8(*(const uint4*)(kp + 8), kv + 8);
      #pragma unroll
      for (int c = 0; c < 16; c++) d += qv[c] * kv[c];
    }
    d += __shfl_xor(d, 1); d += __shfl_xor(d, 2);
    d += __shfl_xor(d, 4); d += __shfl_xor(d, 8);
    sc[rnd] = valid ? d * 0.0625f : -1e30f;
  }
  float m = fmaxf(fmaxf(fmaxf(sc[0], sc[1]), fmaxf(sc[2], sc[3])), sc[4]);
  m = fmaxf(m, __shfl_xor(m, 16));
  m = fmaxf(m, __shfl_xor(m, 32));
  if (t > 16) m = fmaxf(m, 0.0f);
  float ev[5], Zp = 0.f;
  #pragma unroll
  for (int rnd = 0; rnd < 5; rnd++) {
    ev[rnd] = (sc[rnd] > -1e29f) ? __expf(sc[rnd] - m) : 0.f;
    Zp += ev[rnd];
  }
  Zp += __shfl_xor(Zp, 16);
  Zp += __shfl_xor(Zp, 32);
  float e0v = 0.f;
  if (t > 16) { e0v = __expf(-m); Zp += e0v * (float)(t - 16); }
  float vp[16];
  #pragma unroll
  for (int c = 0; c < 16; c++) vp[c] = 0.f;
  #pragma unroll
  for (int rnd = 0; rnd < 5; rnd++) {
    if (ev[rnd] != 0.f) {
      int j = rnd * 4 + g;
      const unsigned short* vpp = qkv + (size_t)(r - 16 + j) * C3_ + 512 + (u << 4);
      float vv[16];
      unpack8(*(const uint4*)vpp, vv);
      unpack8(*(const uint4*)(vpp + 8), vv + 8);
      #pragma unroll
      for (int c = 0; c < 16; c++) vp[c] += ev[rnd] * vv[c];
    }
  }
  #pragma unroll
  for (int c = 0; c < 16; c++) {
    vp[c] += __shfl_xor(vp[c], 16);
    vp[c] += __shfl_xor(vp[c], 32);
  }
  if (g == 0) {
    if (t > 16) {
      const unsigned short* pp = Pb + (size_t)(r - 17) * C_ + (u << 4);
      float pv[16];
      unpack8(*(const uint4*)pp, pv);
      unpack8(*(const uint4*)(pp + 8), pv + 8);
      #pragma unroll
      for (int c = 0; c < 16; c++) vp[c] += e0v * pv[c];
    }
    float inv = 1.0f / Zp;
    const float* gp = gate + (u << 4);
    unsigned int ow[8];
    #pragma unroll
    for (int i = 0; i < 8; i++) {
      unsigned short lo = f2b(vp[2*i] * inv * gp[2*i]);
      unsigned short hi = f2b(vp[2*i+1] * inv * gp[2*i+1]);
      ow[i] = (unsigned int)lo | ((unsigned int)hi << 16);
    }
    uint4 s0 = {ow[0], ow[1], ow[2], ow[3]};
    uint4 s1 = {ow[4], ow[5], ow[6], ow[7]};
    *(uint4*)(aout + (size_t)r * C_ + (u << 4)) = s0;
    *(uint4*)(aout + (size_t)r * C_ + (u << 4) + 8) = s1;
  }
}

// ---------------- 128x128 MFMA GEMM, operand-swapped, swizzled staging ------------------
// EPI 0: outb = bf16(acc + bias)                              (qkv)
// EPI 1: x1 = acc + bias + resid                              (proj)
template<int EPI>
__global__ __launch_bounds__(256) void gemm128(
    const unsigned short* __restrict__ A, const unsigned short* __restrict__ Bt,
    const float* __restrict__ bias, int K, int ldOut,
    const float* __restrict__ resid, float* __restrict__ outf,
    unsigned short* __restrict__ outb) {
  __shared__ __align__(16) unsigned short As[128 * 64];
  __shared__ __align__(16) unsigned short Bs[128 * 64];
  const int tid = threadIdx.x;
  const int wave = tid >> 6, lane = tid & 63;
  const int mBlk = blockIdx.x * 128, nBlk = blockIdx.y * 128;
  const int wm = (wave >> 1) * 64, wn = (wave & 1) * 64;
  const int lm = lane & 15, lk = (lane >> 4) * 8;
  floatx4 acc[4][4];
  #pragma unroll
  for (int i = 0; i < 4; i++)
    #pragma unroll
    for (int j = 0; j < 4; j++) acc[i][j] = (floatx4){0.f, 0.f, 0.f, 0.f};

  for (int kt = 0; kt < K; kt += 64) {
    __syncthreads();
    #pragma unroll
    for (int i = 0; i < 4; i++) {
      int seg = i * 256 + tid;          // 16B segment index
      int row = seg >> 3, g = seg & 7;
      int gc = (g ^ (row & 7)) << 3;    // XOR-swizzle the GLOBAL column (LDS stays linear)
      gl_lds16(A + (size_t)(mBlk + row) * K + kt + gc, &As[seg * 8]);
      gl_lds16(Bt + (size_t)(nBlk + row) * K + kt + gc, &Bs[seg * 8]);
    }
    __syncthreads();
    #pragma unroll
    for (int kk = 0; kk < 64; kk += 32) {
      short8 mf[4], nf[4];
      #pragma unroll
      for (int j = 0; j < 4; j++) {
        int row = wm + j * 16 + lm;
        mf[j] = *(const short8*)&As[row * 64 + ((((kk + lk) >> 3) ^ (row & 7)) << 3)];
      }
      #pragma unroll
      for (int i = 0; i < 4; i++) {
        int row = wn + i * 16 + lm;
        nf[i] = *(const short8*)&Bs[row * 64 + ((((kk + lk) >> 3) ^ (row & 7)) << 3)];
      }
      #pragma unroll
      for (int i = 0; i < 4; i++)
        #pragma unroll
        for (int j = 0; j < 4; j++)
          acc[i][j] = __builtin_amdgcn_mfma_f32_16x16x32_bf16(nf[i], mf[j], acc[i][j], 0, 0, 0);
    }
  }
  const int lc = lane & 15, quad = lane >> 4, q4 = quad * 4;
  #pragma unroll
  for (int i = 0; i < 4; i++) {
    int n0 = nBlk + wn + i * 16 + q4;
    float4 bs = *(const float4*)&bias[n0];
    #pragma unroll
    for (int j = 0; j < 4; j++) {
      int m = mBlk + wm + j * 16 + lc;
      float v0 = acc[i][j][0] + bs.x, v1 = acc[i][j][1] + bs.y;
      float v2 = acc[i][j][2] + bs.z, v3 = acc[i][j][3] + bs.w;
      if (EPI == 0) {
        ushort4 o = {f2b(v0), f2b(v1), f2b(v2), f2b(v3)};
        *(ushort4*)&outb[(size_t)m * ldOut + n0] = o;
      } else {
        size_t idx = (size_t)m * ldOut + n0;
        float4 r = *(const float4*)&resid[idx];
        float4 o = {v0 + r.x, v1 + r.y, v2 + r.z, v3 + r.w};
        *(float4*)&outf[idx] = o;
      }
    }
  }
}

// ---------------- fused MoE, producer/consumer wave split, 16 waves --------------------
// 1024 threads: waves 0-7 = up (h2@w1 + gelu + fp8 -> Hs), waves 8-15 = down (Hs@w2).
// Up: 2 m-groups x 4 h-groups (32m x 16h each); down: 2 m-groups x 4 c-groups (32m x 64c).
// Down lags up by one chunk (Hs double-buffered). W1/W2/b1 double-buffered, counted
// vmcnt(4) prefetch; up A-operand (h2 slice) register-resident.
__global__ __launch_bounds__(1024, 4) void moe_fused(
    const unsigned short* __restrict__ h2,   // [M,256] bf16
    const unsigned short* __restrict__ w1t,  // [4096,256] bf16
    const float* __restrict__ b1,            // [4096] flat
    const unsigned char* __restrict__ w2b,   // [64][256][64] fp8 (x256, seg-swizzled)
    const float* __restrict__ b2,            // [4][256]
    const float* __restrict__ gates,         // [M,4]
    const float* __restrict__ x1,            // [M,256]
    float* __restrict__ out) {
  __shared__ __align__(16) unsigned short W1s[2][64 * 256];    // 64 KB
  __shared__ __align__(16) unsigned char  W2s[2][256 * 64];    // 32 KB
  __shared__ __align__(16) unsigned char  Hs[2][64 * 64];      // 8 KB
  __shared__ __align__(16) float          B1s[2][64];          // 512 B
  const int tid = threadIdx.x;
  const int wave = tid >> 6, lane = tid & 63;
  const int lm = lane & 15, quad = lane >> 4;
  const int mb = blockIdx.x * 64;
  const bool isUp = wave < 8;
  const int rw = wave & 7;
  const int whu = (rw & 3) * 16;      // up h offset (16-col slice)
  const int wmu = (rw >> 2) * 32;     // up m offset (32-row slice)
  const int dwc = (rw & 3) * 64;      // down c offset (64-col slice)
  const int dwm = (rw >> 2) * 32;     // down m offset (32-row slice)

  // stage W1 chunk c + b1 slice into buffer buf: 3 vmem instrs/wave
  auto stageW1 = [&](int c, int buf) {
    const unsigned short* ws = w1t + (size_t)c * 64 * C_;
    #pragma unroll
    for (int t = 0; t < 2; t++) {
      int seg = t * 1024 + tid;
      int row = seg >> 5, g = seg & 31;
      int gp = (g & 24) | ((g & 7) ^ (row & 7));
      gl_lds16(ws + (size_t)row * C_ + gp * 8, &W1s[buf][seg * 8]);
    }
    if (lane < 16)
      gl_lds16(b1 + (size_t)c * 64 + lane * 4, &B1s[buf][0]);
  };
  // stage W2 chunk c into buffer buf: 1 vmem instr/wave (pre-blocked linear 16 KB)
  auto stageW2 = [&](int c, int buf) {
    const unsigned char* vs = w2b + (size_t)c * 256 * 64;
    gl_lds16(vs + (size_t)tid * 16, &W2s[buf][tid * 16]);
  };

  stageW1(0, 0);

  // A-fragments -> registers (up waves): h2 rows [mb+wmu, +32), read once, reused 64 chunks
  short8 af[8][2];
  float4 ga[2];
  if (isUp) {
    #pragma unroll
    for (int kk = 0; kk < 8; kk++) {
      int kc = kk * 4 + quad;
      #pragma unroll
      for (int j = 0; j < 2; j++) {
        int row = mb + wmu + j * 16 + lm;
        af[kk][j] = *(const short8*)(h2 + (size_t)row * C_ + kc * 8);
      }
    }
    #pragma unroll
    for (int j = 0; j < 2; j++)
      ga[j] = *(const float4*)(gates + (size_t)(mb + wmu + j * 16 + lm) * 4);
  }

  floatx4 dacc[4][2];   // [i = c-frag][j = m-frag], down waves only
  #pragma unroll
  for (int i = 0; i < 4; i++)
    #pragma unroll
    for (int j = 0; j < 2; j++) dacc[i][j] = (floatx4){0.f, 0.f, 0.f, 0.f};

  for (int c = 0; c < 64; c++) {
    const int wb = c & 1;
    // (B1): prev iter's Hs writes visible; prev readers done with bufs being restaged
    __builtin_amdgcn_s_barrier();
    __builtin_amdgcn_sched_barrier(0);
    stageW1((c + 1) & 63, wb ^ 1);     // W1/b1 for chunk c+1 (wrap at 63 harmless)
    stageW2(c, wb);                    // W2 for chunk c (consumed next iter)
    asm volatile("s_waitcnt vmcnt(4)" ::: "memory");   // all pre-this-iter loads landed
    // (B2): W1[c], W2[c-1], Hs[c-1] valid for everyone
    __builtin_amdgcn_s_barrier();
    __builtin_amdgcn_sched_barrier(0);

    if (isUp) {
      // ---- up-GEMM chunk c: uacc = h2[32m] x w1[16h], K=256
      floatx4 uacc[2];
      uacc[0] = (floatx4){0.f, 0.f, 0.f, 0.f};
      uacc[1] = (floatx4){0.f, 0.f, 0.f, 0.f};
      #pragma unroll
      for (int kk = 0; kk < 8; kk++) {
        int kc = kk * 4 + quad;
        int row = whu + lm;
        short8 nf = *(const short8*)&W1s[wb][row * 256 + ((kc ^ (row & 7)) << 3)];
        #pragma unroll
        for (int j = 0; j < 2; j++)
          uacc[j] = __builtin_amdgcn_mfma_f32_16x16x32_bf16(nf, af[kk][j], uacc[j], 0, 0, 0);
      }
      // ---- gelu + gate + fp8 -> Hs[wb], XOR-swizzled 8B granules
      int e = c >> 4;
      float4 bb = *(const float4*)&B1s[wb][whu + quad * 4];
      #pragma unroll
      for (int j = 0; j < 2; j++) {
        float gs = 64.0f * sel4(ga[j], e);
        unsigned int w = pk_fp8x4(gs * gelu_s(uacc[j][0] + bb.x),
                                  gs * gelu_s(uacc[j][1] + bb.y),
                                  gs * gelu_s(uacc[j][2] + bb.z),
                                  gs * gelu_s(uacc[j][3] + bb.w));
        int m = wmu + j * 16 + lm;
        int hh = whu + quad * 4;
        *(unsigned int*)&Hs[wb][m * 64 + ((((hh >> 3) ^ (m & 7)) << 3) | (hh & 7))] = w;
      }
      asm volatile("s_waitcnt lgkmcnt(0)" ::: "memory");   // Hs writes landed before B1
    } else if (c > 0) {
      // ---- down-GEMM chunk c-1: dacc += hid8[32m x 64k] x w2[64c x 64k] (fp8)
      const int pb = wb ^ 1;
      #pragma unroll
      for (int kk = 0; kk < 2; kk++) {
        long mfh[2], nfw[4];
        #pragma unroll
        for (int j = 0; j < 2; j++) {
          int m = dwm + j * 16 + lm;
          int g8 = quad + 4 * kk;
          mfh[j] = *(const long*)&Hs[pb][m * 64 + ((g8 ^ (m & 7)) << 3)];
        }
        #pragma unroll
        for (int i = 0; i < 4; i++) {
          int cr = dwc + i * 16 + lm;
          int sl = ((quad >> 1) + 2 * kk) ^ ((cr >> 1) & 3);
          nfw[i] = *(const long*)&W2s[pb][cr * 64 + (sl << 4) + ((quad & 1) << 3)];
        }
        #pragma unroll
        for (int i = 0; i < 4; i++)
          #pragma unroll
          for (int j = 0; j < 2; j++)
            dacc[i][j] = __builtin_amdgcn_mfma_f32_16x16x32_fp8_fp8(nfw[i], mfh[j], dacc[i][j], 0, 0, 0);
      }
    }
  }

  // ---- drain: final down step for chunk 63 (Hs[1], W2s[1]), then epilogue
  asm volatile("s_waitcnt vmcnt(0)" ::: "memory");
  __builtin_amdgcn_s_barrier();
  __builtin_amdgcn_sched_barrier(0);
  if (!isUp) {
    #pragma unroll
    for (int kk = 0; kk < 2; kk++) {
      long mfh[2], nfw[4];
      #pragma unroll
      for (int j = 0; j < 2; j++) {
        int m = dwm + j * 16 + lm;
        int g8 = quad + 4 * kk;
        mfh[j] = *(const long*)&Hs[1][m * 64 + ((g8 ^ (m & 7)) << 3)];
      }
      #pragma unroll
      for (int i = 0; i < 4; i++) {
        int cr = dwc + i * 16 + lm;
        int sl = ((quad >> 1) + 2 * kk) ^ ((cr >> 1) & 3);
        nfw[i] = *(const long*)&W2s[1][cr * 64 + (sl << 4) + ((quad & 1) << 3)];
      }
      #pragma unroll
      for (int i = 0; i < 4; i++)
        #pragma unroll
        for (int j = 0; j < 2; j++)
          dacc[i][j] = __builtin_amdgcn_mfma_f32_16x16x32_fp8_fp8(nfw[i], mfh[j], dacc[i][j], 0, 0, 0);
    }
    // ---- epilogue: out = dacc/2^14 + x1 + sum_e gate_e * b2_e
    const float sc = 1.0f / 16384.0f;
    const int q4 = quad * 4;
    #pragma unroll
    for (int j = 0; j < 2; j++) {
      int m = mb + dwm + j * 16 + lm;
      float4 g4 = *(const float4*)(gates + (size_t)m * 4);
      #pragma unroll
      for (int i = 0; i < 4; i++) {
        int n0 = dwc + i * 16 + q4;
        float4 bA = *(const float4*)&b2[0 * C_ + n0];
        float4 bB = *(const float4*)&b2[1 * C_ + n0];
        float4 bC = *(const float4*)&b2[2 * C_ + n0];
        float4 bD = *(const float4*)&b2[3 * C_ + n0];
        size_t idx = (size_t)m * C_ + n0;
        float4 r = *(const float4*)&x1[idx];
        float4 o;
        o.x = dacc[i][j][0]*sc + r.x + g4.x*bA.x + g4.y*bB.x + g4.z*bC.x + g4.w*bD.x;
        o.y = dacc[i][j][1]*sc + r.y + g4.x*bA.y + g4.y*bB.y + g4.z*bC.y + g4.w*bD.y;
        o.z = dacc[i][j][2]*sc + r.z + g4.x*bA.z + g4.y*bB.z + g4.z*bC.z + g4.w*bD.z;
        o.w = dacc[i][j][3]*sc + r.w + g4.x*bA.w + g4.y*bB.w + g4.z*bC.w + g4.w*bD.w;
        *(float4*)&out[idx] = o;
      }
    }
  }
}

extern "C" void kernel_launch(void* const* d_in, const int* in_sizes, int n_in,
                              void* d_out, int out_size, void* d_ws, size_t ws_size,
                              hipStream_t stream) {
  const float* x       = (const float*)d_in[0];
  const float* ln1_g   = (const float*)d_in[1];
  const float* ln1_b   = (const float*)d_in[2];
  const float* qkv_w   = (const float*)d_in[3];
  const float* qkv_b   = (const float*)d_in[4];
  const float* proj_w  = (const float*)d_in[5];
  const float* proj_b  = (const float*)d_in[6];
  const float* attn_g  = (const float*)d_in[7];
  const float* ln2_g   = (const float*)d_in[8];
  const float* ln2_b   = (const float*)d_in[9];
  const float* gat_w   = (const float*)d_in[10];
  const float* gat_b   = (const float*)d_in[11];
  const float* e_w1    = (const float*)d_in[12];
  const float* e_b1    = (const float*)d_in[13];
  const float* e_w2    = (const float*)d_in[14];
  const float* e_b2    = (const float*)d_in[15];
  float* out = (float*)d_out;

  char* p = (char*)d_ws;
  unsigned short* h    = (unsigned short*)p; p += (size_t)M_ * C_ * 2;      // 8 MB
  unsigned short* qkv  = (unsigned short*)p; p += (size_t)M_ * C3_ * 2;     // 24 MB
  unsigned short* Pb   = (unsigned short*)p; p += (size_t)M_ * C_ * 2;      // 8 MB
  unsigned short* aout = (unsigned short*)p; p += (size_t)M_ * C_ * 2;      // 8 MB
  float*          x1   = (float*)p;          p += (size_t)M_ * C_ * 4;      // 16 MB
  unsigned short* h2   = (unsigned short*)p; p += (size_t)M_ * C_ * 2;      // 8 MB
  float*          gts  = (float*)p;          p += (size_t)M_ * E_ * 4;      // 256 KB
  float*          S    = (float*)p;          p += (size_t)B_ * NCH_ * C_ * 4;
  unsigned short* wq   = (unsigned short*)p; p += (size_t)C3_ * C_ * 2;
  unsigned short* wp   = (unsigned short*)p; p += (size_t)C_ * C_ * 2;
  unsigned short* w1t  = (unsigned short*)p; p += (size_t)KH_ * C_ * 2;     // 2 MB [4096,256]
  unsigned char*  w2f8 = (unsigned char*)p;  p += (size_t)C_ * KH_;         // 1 MB blocked

  dim3 t32x8(32, 8);
  transpose_cvt<<<dim3(C3_/32, C_/32, 1), t32x8, 0, stream>>>(qkv_w, wq, C_, C3_, C_, 0);
  transpose_cvt<<<dim3(C_/32, C_/32, 1),  t32x8, 0, stream>>>(proj_w, wp, C_, C_, C_, 0);
  // w1t[e*1024 + hrow][c]  (flat [4096, 256]) bf16
  transpose_cvt<<<dim3(H_/32, C_/32, E_), t32x8, 0, stream>>>(e_w1, w1t, C_, H_, C_, (size_t)H_ * C_);
  // w2 -> fp8 x256, blocked [chunk][c][64] with seg swizzle
  transpose_w2_fp8<<<dim3(H_/32, C_/32, E_), t32x8, 0, stream>>>(e_w2, w2f8);

  ln1_kernel<<<M_, 256, 0, stream>>>(x, ln1_g, ln1_b, h);
  gemm128<0><<<dim3(M_/128, C3_/128), 256, 0, stream>>>(h, wq, qkv_b, C_, C3_,
      nullptr, nullptr, qkv);
  scan1_kernel<<<B_*NCH_, 256, 0, stream>>>(qkv, S);
  scan2_kernel<<<B_, 256, 0, stream>>>(S);
  scan3_kernel<<<B_*NCH_, 256, 0, stream>>>(qkv, S, Pb);
  attn_kernel<<<M_/4, 256, 0, stream>>>(qkv, Pb, attn_g, aout);
  // x1 = x + aout @ proj_w + proj_b
  gemm128<1><<<dim3(M_/128, C_/128), 256, 0, stream>>>(aout, wp, proj_b, C_, C_,
      x, x1, nullptr);
  ln2_gates_kernel<<<M_, 256, 0, stream>>>(x1, ln2_g, ln2_b, gat_w, gat_b, h2, gts);
  // fused MoE: 8 producer waves (up+gelu+fp8) || 8 consumer waves (down), Hs dbuf
  moe_fused<<<M_/64, 1024, 0, stream>>>(h2, w1t, e_b1, w2f8, e_b2, gts, x1, out);
}

// Round 4
// 330.131 us; speedup vs baseline: 1.2073x; 1.2073x over previous
//
#include <hip/hip_runtime.h>
#include <hip/hip_bf16.h>
#include <math.h>

#define T_   4096
#define B_   4
#define C_   256
#define C3_  768
#define H_   1024
#define E_   4
#define M_   (B_*T_)      // 16384 rows
#define NCH_ 64
#define CHL_ (T_/NCH_)    // 64
#define KH_  4096         // E*H

typedef __attribute__((ext_vector_type(8))) short short8;
typedef __attribute__((ext_vector_type(4))) float floatx4;

__device__ __forceinline__ float b2f(unsigned short u) {
  union { unsigned int i; float f; } x; x.i = ((unsigned int)u) << 16; return x.f;
}
__device__ __forceinline__ unsigned short f2b(float f) {
  __hip_bfloat16 h = __float2bfloat16(f);
  return *reinterpret_cast<unsigned short*>(&h);
}
__device__ __forceinline__ void unpack8(uint4 a, float* f) {
  unsigned int w[4] = {a.x, a.y, a.z, a.w};
  #pragma unroll
  for (int i = 0; i < 4; i++) {
    union { unsigned int u; float g; } lo, hi;
    lo.u = w[i] << 16; hi.u = w[i] & 0xffff0000u;
    f[2*i] = lo.g; f[2*i+1] = hi.g;
  }
}
__device__ __forceinline__ void gl_lds16(const void* g, void* l) {
  __builtin_amdgcn_global_load_lds(
      (const __attribute__((address_space(1))) void*)g,
      (__attribute__((address_space(3))) void*)l, 16, 0, 0);
}
// sigmoid GELU: x*sigma(1.702x). |err|<=~0.01 on hid; attenuated by zero-mean w2 down-sum.
// Numerics verified on HW: passed with absmax 0.03125 using this form.
__device__ __forceinline__ float gelu_s(float v) {
  float e = __expf(-1.702f * v);
  return v * __builtin_amdgcn_rcpf(1.0f + e);
}
// pack 4 floats -> 4 fp8 e4m3 (OCP) in one uint
__device__ __forceinline__ unsigned int pk_fp8x4(float a, float b, float c, float d) {
  unsigned int v = 0;
  v = __builtin_amdgcn_cvt_pk_fp8_f32(a, b, v, false);
  v = __builtin_amdgcn_cvt_pk_fp8_f32(c, d, v, true);
  return v;
}
__device__ __forceinline__ unsigned char f2fp8(float v) {
  return (unsigned char)(__builtin_amdgcn_cvt_pk_fp8_f32(v, v, 0, false) & 0xff);
}
__device__ __forceinline__ float sel4(float4 v, int e) {
  float r = v.x;
  r = (e == 1) ? v.y : r;
  r = (e == 2) ? v.z : r;
  r = (e == 3) ? v.w : r;
  return r;
}

// ---------------- transpose + fp32->bf16: src[K,N](+z*K*N) -> dst[+z*zStr][n*dstLd + k] ----
__global__ __launch_bounds__(256) void transpose_cvt(
    const float* __restrict__ src, unsigned short* __restrict__ dst, int K, int N,
    int dstLd, size_t dstZStride) {
  __shared__ float tile[32][33];
  src += (size_t)blockIdx.z * K * N;
  dst += (size_t)blockIdx.z * dstZStride;
  int n0 = blockIdx.x * 32, k0 = blockIdx.y * 32;
  int tx = threadIdx.x, ty = threadIdx.y;   // blockDim (32,8)
  #pragma unroll
  for (int i = 0; i < 32; i += 8)
    tile[ty + i][tx] = src[(size_t)(k0 + ty + i) * N + n0 + tx];
  __syncthreads();
  #pragma unroll
  for (int i = 0; i < 32; i += 8)
    dst[(size_t)(n0 + ty + i) * dstLd + k0 + tx] = f2b(tile[tx][ty + i]);
}

// ---------------- w2 -> fp8 blocked: w2b[chunk=k>>5][c][32 bytes, granule-swizzled] ------
// value = fp8(w2[e][h][c] * 256), k = e*1024+h.  Within the 32-byte row the 8B granule g
// is stored at g ^ ((c>>2)&3): the down-GEMM reads 16 consecutive c-rows per lane-group
// -> base bank (c&3)*8 plus granule slot distinct per (c>>2)&3 -> conflict-free.
__global__ __launch_bounds__(256) void transpose_w2_fp8(
    const float* __restrict__ src, unsigned char* __restrict__ dst) {
  __shared__ float tile[32][33];
  int e = blockIdx.z;
  src += (size_t)e * H_ * C_;
  int h0 = blockIdx.x * 32, c0 = blockIdx.y * 32;
  int tx = threadIdx.x, ty = threadIdx.y;
  #pragma unroll
  for (int i = 0; i < 32; i += 8)
    tile[ty + i][tx] = src[(size_t)(h0 + ty + i) * C_ + c0 + tx];
  __syncthreads();
  int k = e * H_ + h0 + tx;
  int chunk = k >> 5, kc = k & 31;
  #pragma unroll
  for (int i = 0; i < 32; i += 8) {
    int c = c0 + ty + i;
    int sw = ((((kc >> 3) ^ ((c >> 2) & 3)) << 3) | (kc & 7));
    dst[((size_t)chunk * 256 + c) * 32 + sw] = f2fp8(tile[tx][ty + i] * 256.0f);
  }
}

// ---------------- LayerNorm 1 ----------------
__global__ __launch_bounds__(256) void ln1_kernel(
    const float* __restrict__ x, const float* __restrict__ g,
    const float* __restrict__ b, unsigned short* __restrict__ h) {
  __shared__ float red[4];
  int row = blockIdx.x, tid = threadIdx.x;
  float v = x[(size_t)row * C_ + tid];
  float s = v;
  #pragma unroll
  for (int o = 32; o; o >>= 1) s += __shfl_xor(s, o);
  if ((tid & 63) == 0) red[tid >> 6] = s;
  __syncthreads();
  float mean = (red[0] + red[1] + red[2] + red[3]) * (1.0f / C_);
  __syncthreads();
  float d = v - mean;
  float q = d * d;
  #pragma unroll
  for (int o = 32; o; o >>= 1) q += __shfl_xor(q, o);
  if ((tid & 63) == 0) red[tid >> 6] = q;
  __syncthreads();
  float var = (red[0] + red[1] + red[2] + red[3]) * (1.0f / C_);
  h[(size_t)row * C_ + tid] = f2b(d * rsqrtf(var + 1e-5f) * g[tid] + b[tid]);
}

// ---------------- LayerNorm 2 + gating softmax (h2 bf16) ----------------
__global__ __launch_bounds__(256) void ln2_gates_kernel(
    const float* __restrict__ x1, const float* __restrict__ g,
    const float* __restrict__ b, const float* __restrict__ gw,
    const float* __restrict__ gb, unsigned short* __restrict__ h2,
    float* __restrict__ gates) {
  __shared__ float red[4];
  __shared__ float redg[4][4];
  int row = blockIdx.x, tid = threadIdx.x;
  float v = x1[(size_t)row * C_ + tid];
  float s = v;
  #pragma unroll
  for (int o = 32; o; o >>= 1) s += __shfl_xor(s, o);
  if ((tid & 63) == 0) red[tid >> 6] = s;
  __syncthreads();
  float mean = (red[0] + red[1] + red[2] + red[3]) * (1.0f / C_);
  __syncthreads();
  float d = v - mean;
  float q = d * d;
  #pragma unroll
  for (int o = 32; o; o >>= 1) q += __shfl_xor(q, o);
  if ((tid & 63) == 0) red[tid >> 6] = q;
  __syncthreads();
  float var = (red[0] + red[1] + red[2] + red[3]) * (1.0f / C_);
  float hv = d * rsqrtf(var + 1e-5f) * g[tid] + b[tid];
  h2[(size_t)row * C_ + tid] = f2b(hv);
  float p0 = hv * gw[tid * 4 + 0];
  float p1 = hv * gw[tid * 4 + 1];
  float p2 = hv * gw[tid * 4 + 2];
  float p3 = hv * gw[tid * 4 + 3];
  #pragma unroll
  for (int o = 32; o; o >>= 1) {
    p0 += __shfl_xor(p0, o); p1 += __shfl_xor(p1, o);
    p2 += __shfl_xor(p2, o); p3 += __shfl_xor(p3, o);
  }
  if ((tid & 63) == 0) {
    int w = tid >> 6;
    redg[w][0] = p0; redg[w][1] = p1; redg[w][2] = p2; redg[w][3] = p3;
  }
  __syncthreads();
  if (tid == 0) {
    float t4[4];
    #pragma unroll
    for (int e = 0; e < 4; e++)
      t4[e] = redg[0][e] + redg[1][e] + redg[2][e] + redg[3][e] + gb[e];
    float m = fmaxf(fmaxf(t4[0], t4[1]), fmaxf(t4[2], t4[3]));
    float zs = 0.f;
    #pragma unroll
    for (int e = 0; e < 4; e++) { t4[e] = __expf(t4[e] - m); zs += t4[e]; }
    float inv = 1.0f / zs;
    #pragma unroll
    for (int e = 0; e < 4; e++) gates[(size_t)row * 4 + e] = t4[e] * inv;
  }
}

// ---------------- chunked prefix scan of v ----------------
__global__ __launch_bounds__(256) void scan1_kernel(const unsigned short* __restrict__ qkv,
                                                    float* __restrict__ S) {
  int b = blockIdx.x >> 6, ch = blockIdx.x & 63, c = threadIdx.x;
  float s = 0.f;
  size_t base = ((size_t)b * T_ + (size_t)ch * CHL_) * C3_ + 512 + c;
  for (int t = 0; t < CHL_; t++) s += b2f(qkv[base + (size_t)t * C3_]);
  S[((size_t)b * NCH_ + ch) * C_ + c] = s;
}
__global__ __launch_bounds__(256) void scan2_kernel(float* __restrict__ S) {
  int b = blockIdx.x, c = threadIdx.x;
  float run = 0.f;
  for (int ch = 0; ch < NCH_; ch++) {
    size_t i = ((size_t)b * NCH_ + ch) * C_ + c;
    float t = S[i]; S[i] = run; run += t;
  }
}
__global__ __launch_bounds__(256) void scan3_kernel(const unsigned short* __restrict__ qkv,
                                                    const float* __restrict__ S,
                                                    unsigned short* __restrict__ Pb) {
  int b = blockIdx.x >> 6, ch = blockIdx.x & 63, c = threadIdx.x;
  float run = S[((size_t)b * NCH_ + ch) * C_ + c];
  size_t row0 = (size_t)b * T_ + (size_t)ch * CHL_;
  for (int t = 0; t < CHL_; t++) {
    run += b2f(qkv[(row0 + t) * C3_ + 512 + c]);
    Pb[(row0 + t) * C_ + c] = f2b(run);
  }
}

// ---------------- windowed attention: 16-lane group per window position ----------------
__global__ __launch_bounds__(256) void attn_kernel(
    const unsigned short* __restrict__ qkv, const unsigned short* __restrict__ Pb,
    const float* __restrict__ gate, unsigned short* __restrict__ aout) {
  int wave = threadIdx.x >> 6, lane = threadIdx.x & 63;
  int r = blockIdx.x * 4 + wave;
  int t = r & (T_ - 1);
  int g = lane >> 4, u = lane & 15;
  const unsigned short* qp = qkv + (size_t)r * C3_ + (u << 4);
  float qv[16];
  unpack8(*(const uint4*)qp, qv);
  unpack8(*(const uint4*)(qp + 8), qv + 8);
  float sc[5];
  #pragma unroll
  for (int rnd = 0; rnd < 5; rnd++) {
    int j = rnd * 4 + g;
    int jj = t - 16 + j;
    bool valid = (j <= 16) && (jj >= 0);
    float d = 0.f;
    if (valid) {
      const unsigned short* kp = qkv + (size_t)(r - 16 + j) * C3_ + 256 + (u << 4);
      float kv[16];
      unpack8(*(const uint4*)kp, kv);
      unpack8(*(const uint4*)(kp + 8), kv + 8);
      #pragma unroll
      for (int c = 0; c < 16; c++) d += qv[c] * kv[c];
    }
    d += __shfl_xor(d, 1); d += __shfl_xor(d, 2);
    d += __shfl_xor(d, 4); d += __shfl_xor(d, 8);
    sc[rnd] = valid ? d * 0.0625f : -1e30f;
  }
  float m = fmaxf(fmaxf(fmaxf(sc[0], sc[1]), fmaxf(sc[2], sc[3])), sc[4]);
  m = fmaxf(m, __shfl_xor(m, 16));
  m = fmaxf(m, __shfl_xor(m, 32));
  if (t > 16) m = fmaxf(m, 0.0f);
  float ev[5], Zp = 0.f;
  #pragma unroll
  for (int rnd = 0; rnd < 5; rnd++) {
    ev[rnd] = (sc[rnd] > -1e29f) ? __expf(sc[rnd] - m) : 0.f;
    Zp += ev[rnd];
  }
  Zp += __shfl_xor(Zp, 16);
  Zp += __shfl_xor(Zp, 32);
  float e0v = 0.f;
  if (t > 16) { e0v = __expf(-m); Zp += e0v * (float)(t - 16); }
  float vp[16];
  #pragma unroll
  for (int c = 0; c < 16; c++) vp[c] = 0.f;
  #pragma unroll
  for (int rnd = 0; rnd < 5; rnd++) {
    if (ev[rnd] != 0.f) {
      int j = rnd * 4 + g;
      const unsigned short* vpp = qkv + (size_t)(r - 16 + j) * C3_ + 512 + (u << 4);
      float vv[16];
      unpack8(*(const uint4*)vpp, vv);
      unpack8(*(const uint4*)(vpp + 8), vv + 8);
      #pragma unroll
      for (int c = 0; c < 16; c++) vp[c] += ev[rnd] * vv[c];
    }
  }
  #pragma unroll
  for (int c = 0; c < 16; c++) {
    vp[c] += __shfl_xor(vp[c], 16);
    vp[c] += __shfl_xor(vp[c], 32);
  }
  if (g == 0) {
    if (t > 16) {
      const unsigned short* pp = Pb + (size_t)(r - 17) * C_ + (u << 4);
      float pv[16];
      unpack8(*(const uint4*)pp, pv);
      unpack8(*(const uint4*)(pp + 8), pv + 8);
      #pragma unroll
      for (int c = 0; c < 16; c++) vp[c] += e0v * pv[c];
    }
    float inv = 1.0f / Zp;
    const float* gp = gate + (u << 4);
    unsigned int ow[8];
    #pragma unroll
    for (int i = 0; i < 8; i++) {
      unsigned short lo = f2b(vp[2*i] * inv * gp[2*i]);
      unsigned short hi = f2b(vp[2*i+1] * inv * gp[2*i+1]);
      ow[i] = (unsigned int)lo | ((unsigned int)hi << 16);
    }
    uint4 s0 = {ow[0], ow[1], ow[2], ow[3]};
    uint4 s1 = {ow[4], ow[5], ow[6], ow[7]};
    *(uint4*)(aout + (size_t)r * C_ + (u << 4)) = s0;
    *(uint4*)(aout + (size_t)r * C_ + (u << 4) + 8) = s1;
  }
}

// ---------------- 128x128 MFMA GEMM, operand-swapped, swizzled staging ------------------
// EPI 0: outb = bf16(acc + bias)                              (qkv)
// EPI 1: x1 = acc + bias + resid                              (proj)
template<int EPI>
__global__ __launch_bounds__(256) void gemm128(
    const unsigned short* __restrict__ A, const unsigned short* __restrict__ Bt,
    const float* __restrict__ bias, int K, int ldOut,
    const float* __restrict__ resid, float* __restrict__ outf,
    unsigned short* __restrict__ outb) {
  __shared__ __align__(16) unsigned short As[128 * 64];
  __shared__ __align__(16) unsigned short Bs[128 * 64];
  const int tid = threadIdx.x;
  const int wave = tid >> 6, lane = tid & 63;
  const int mBlk = blockIdx.x * 128, nBlk = blockIdx.y * 128;
  const int wm = (wave >> 1) * 64, wn = (wave & 1) * 64;
  const int lm = lane & 15, lk = (lane >> 4) * 8;
  floatx4 acc[4][4];
  #pragma unroll
  for (int i = 0; i < 4; i++)
    #pragma unroll
    for (int j = 0; j < 4; j++) acc[i][j] = (floatx4){0.f, 0.f, 0.f, 0.f};

  for (int kt = 0; kt < K; kt += 64) {
    __syncthreads();
    #pragma unroll
    for (int i = 0; i < 4; i++) {
      int seg = i * 256 + tid;          // 16B segment index
      int row = seg >> 3, g = seg & 7;
      int gc = (g ^ (row & 7)) << 3;    // XOR-swizzle the GLOBAL column (LDS stays linear)
      gl_lds16(A + (size_t)(mBlk + row) * K + kt + gc, &As[seg * 8]);
      gl_lds16(Bt + (size_t)(nBlk + row) * K + kt + gc, &Bs[seg * 8]);
    }
    __syncthreads();
    #pragma unroll
    for (int kk = 0; kk < 64; kk += 32) {
      short8 mf[4], nf[4];
      #pragma unroll
      for (int j = 0; j < 4; j++) {
        int row = wm + j * 16 + lm;
        mf[j] = *(const short8*)&As[row * 64 + ((((kk + lk) >> 3) ^ (row & 7)) << 3)];
      }
      #pragma unroll
      for (int i = 0; i < 4; i++) {
        int row = wn + i * 16 + lm;
        nf[i] = *(const short8*)&Bs[row * 64 + ((((kk + lk) >> 3) ^ (row & 7)) << 3)];
      }
      #pragma unroll
      for (int i = 0; i < 4; i++)
        #pragma unroll
        for (int j = 0; j < 4; j++)
          acc[i][j] = __builtin_amdgcn_mfma_f32_16x16x32_bf16(nf[i], mf[j], acc[i][j], 0, 0, 0);
    }
  }
  const int lc = lane & 15, quad = lane >> 4, q4 = quad * 4;
  #pragma unroll
  for (int i = 0; i < 4; i++) {
    int n0 = nBlk + wn + i * 16 + q4;
    float4 bs = *(const float4*)&bias[n0];
    #pragma unroll
    for (int j = 0; j < 4; j++) {
      int m = mBlk + wm + j * 16 + lc;
      float v0 = acc[i][j][0] + bs.x, v1 = acc[i][j][1] + bs.y;
      float v2 = acc[i][j][2] + bs.z, v3 = acc[i][j][3] + bs.w;
      if (EPI == 0) {
        ushort4 o = {f2b(v0), f2b(v1), f2b(v2), f2b(v3)};
        *(ushort4*)&outb[(size_t)m * ldOut + n0] = o;
      } else {
        size_t idx = (size_t)m * ldOut + n0;
        float4 r = *(const float4*)&resid[idx];
        float4 o = {v0 + r.x, v1 + r.y, v2 + r.z, v3 + r.w};
        *(float4*)&outf[idx] = o;
      }
    }
  }
}

// ---------------- fused MoE, producer/consumer wave split, 2 blocks/CU ------------------
// 512 threads, 32 M-rows/block, grid 512 (= 2 independent blocks per CU -> phase overlap).
// Waves 0-3 = up (h2@w1 + gelu + fp8 -> Hs), each 16m x 16h per 32h-chunk.
// Waves 4-7 = down (Hs@w2 -> dacc), each 32m x 64c, lagging one chunk (Hs dbuf).
// 128 chunks of 32 hid dims. W1/W2/b1 double-buffered, counted vmcnt(4) prefetch.
// LDS 50.75 KB -> 2 blocks/CU; __launch_bounds__(512,4) caps VGPR at 128 (no spill).
__global__ __launch_bounds__(512, 4) void moe_fused(
    const unsigned short* __restrict__ h2,   // [M,256] bf16
    const unsigned short* __restrict__ w1t,  // [4096,256] bf16
    const float* __restrict__ b1,            // [4096] flat
    const unsigned char* __restrict__ w2b,   // [128][256][32] fp8 (x256, granule-swizzled)
    const float* __restrict__ b2,            // [4][256]
    const float* __restrict__ gates,         // [M,4]
    const float* __restrict__ x1,            // [M,256]
    float* __restrict__ out) {
  __shared__ __align__(16) unsigned short W1s[2][32 * 256];    // 32 KB
  __shared__ __align__(16) unsigned char  W2s[2][256 * 32];    // 16 KB
  __shared__ __align__(16) unsigned char  Hs[2][32 * 40];      // 2.5 KB (rows padded to 40B)
  __shared__ __align__(16) float          B1s[2][32];          // 256 B
  const int tid = threadIdx.x;
  const int wave = tid >> 6, lane = tid & 63;
  const int lm = lane & 15, quad = lane >> 4;
  const int mb = blockIdx.x * 32;
  const bool isUp = wave < 4;
  const int rw = wave & 3;
  const int wmu = (rw >> 1) * 16;     // up m offset (16-row slice)
  const int whu = (rw & 1) * 16;      // up h offset (16-col slice)
  const int dwc = rw * 64;            // down c offset (64-col slice)

  // stage W1 chunk c (32 rows x 256 K) + b1 slice: 3 vmem instrs/wave
  auto stageW1 = [&](int c, int buf) {
    const unsigned short* ws = w1t + (size_t)c * 32 * C_;
    #pragma unroll
    for (int t = 0; t < 2; t++) {
      int seg = t * 512 + tid;
      int row = seg >> 5, g = seg & 31;
      int gp = (g & 24) | ((g & 7) ^ (row & 7));
      gl_lds16(ws + (size_t)row * C_ + gp * 8, &W1s[buf][seg * 8]);
    }
    if (lane < 8)
      gl_lds16(b1 + (size_t)c * 32 + lane * 4, &B1s[buf][0]);
  };
  // stage W2 chunk c (256 c x 32 k fp8 = 8 KB, pre-blocked linear): 1 vmem instr/wave
  auto stageW2 = [&](int c, int buf) {
    const unsigned char* vs = w2b + (size_t)c * 256 * 32;
    gl_lds16(vs + (size_t)tid * 16, &W2s[buf][tid * 16]);
  };

  stageW1(0, 0);

  // A-fragments -> registers (up waves): h2 rows [mb+wmu, +16), read once, reused 128x
  short8 af[8];
  float4 ga;
  if (isUp) {
    int row = mb + wmu + lm;
    #pragma unroll
    for (int kk = 0; kk < 8; kk++)
      af[kk] = *(const short8*)(h2 + (size_t)row * C_ + (kk * 4 + quad) * 8);
    ga = *(const float4*)(gates + (size_t)row * 4);
  }

  floatx4 dacc[4][2];   // [i = c-frag][j = m-frag], down waves only
  #pragma unroll
  for (int i = 0; i < 4; i++)
    #pragma unroll
    for (int j = 0; j < 2; j++) dacc[i][j] = (floatx4){0.f, 0.f, 0.f, 0.f};

  asm volatile("s_waitcnt vmcnt(0)" ::: "memory");
  __builtin_amdgcn_s_barrier();
  __builtin_amdgcn_sched_barrier(0);

  for (int c = 0; c < 128; c++) {
    const int wb = c & 1;
    // (B1): prev iter's Hs writes visible; prev readers done with bufs being restaged
    __builtin_amdgcn_s_barrier();
    __builtin_amdgcn_sched_barrier(0);
    stageW1((c + 1) & 127, wb ^ 1);    // W1/b1 for chunk c+1 (wrap harmless)
    stageW2(c, wb);                    // W2 for chunk c (consumed next iter)
    asm volatile("s_waitcnt vmcnt(4)" ::: "memory");   // prev-iter loads landed
    // (B2): W1[c], W2[c-1], Hs[c-1] valid for everyone
    __builtin_amdgcn_s_barrier();
    __builtin_amdgcn_sched_barrier(0);

    if (isUp) {
      // ---- up-GEMM chunk c: uacc = h2[16m] x w1[16h], K=256
      floatx4 uacc = (floatx4){0.f, 0.f, 0.f, 0.f};
      #pragma unroll
      for (int kk = 0; kk < 8; kk++) {
        int kc = kk * 4 + quad;
        int row = whu + lm;
        short8 nf = *(const short8*)&W1s[wb][row * 256 + ((kc ^ (row & 7)) << 3)];
        uacc = __builtin_amdgcn_mfma_f32_16x16x32_bf16(nf, af[kk], uacc, 0, 0, 0);
      }
      // ---- gelu + gate + fp8 -> Hs[wb] (rows 40B, linear h, bank-spread by pad)
      int e = c >> 5;
      float4 bb = *(const float4*)&B1s[wb][whu + quad * 4];
      float gs = 64.0f * sel4(ga, e);
      unsigned int w = pk_fp8x4(gs * gelu_s(uacc[0] + bb.x),
                                gs * gelu_s(uacc[1] + bb.y),
                                gs * gelu_s(uacc[2] + bb.z),
                                gs * gelu_s(uacc[3] + bb.w));
      int m = wmu + lm;
      *(unsigned int*)&Hs[wb][m * 40 + whu + quad * 4] = w;
      asm volatile("s_waitcnt lgkmcnt(0)" ::: "memory");   // Hs writes landed before B1
    } else if (c > 0) {
      // ---- down-GEMM chunk c-1: dacc += hid8[32m x 32k] x w2[256c x 32k] (fp8)
      const int pb = wb ^ 1;
      long mfh[2], nfw[4];
      #pragma unroll
      for (int j = 0; j < 2; j++) {
        int m = j * 16 + lm;
        mfh[j] = *(const long*)&Hs[pb][m * 40 + quad * 8];
      }
      #pragma unroll
      for (int i = 0; i < 4; i++) {
        int cr = dwc + i * 16 + lm;
        int sl = quad ^ ((cr >> 2) & 3);
        nfw[i] = *(const long*)&W2s[pb][cr * 32 + (sl << 3)];
      }
      #pragma unroll
      for (int i = 0; i < 4; i++)
        #pragma unroll
        for (int j = 0; j < 2; j++)
          dacc[i][j] = __builtin_amdgcn_mfma_f32_16x16x32_fp8_fp8(nfw[i], mfh[j], dacc[i][j], 0, 0, 0);
    }
  }

  // ---- drain: final down step for chunk 127 (Hs[1], W2s[1]), then epilogue
  asm volatile("s_waitcnt vmcnt(0)" ::: "memory");
  __builtin_amdgcn_s_barrier();
  __builtin_amdgcn_sched_barrier(0);
  if (!isUp) {
    long mfh[2], nfw[4];
    #pragma unroll
    for (int j = 0; j < 2; j++) {
      int m = j * 16 + lm;
      mfh[j] = *(const long*)&Hs[1][m * 40 + quad * 8];
    }
    #pragma unroll
    for (int i = 0; i < 4; i++) {
      int cr = dwc + i * 16 + lm;
      int sl = quad ^ ((cr >> 2) & 3);
      nfw[i] = *(const long*)&W2s[1][cr * 32 + (sl << 3)];
    }
    #pragma unroll
    for (int i = 0; i < 4; i++)
      #pragma unroll
      for (int j = 0; j < 2; j++)
        dacc[i][j] = __builtin_amdgcn_mfma_f32_16x16x32_fp8_fp8(nfw[i], mfh[j], dacc[i][j], 0, 0, 0);
    // ---- epilogue: out = dacc/2^14 + x1 + sum_e gate_e * b2_e
    const float sc = 1.0f / 16384.0f;
    const int q4 = quad * 4;
    #pragma unroll
    for (int j = 0; j < 2; j++) {
      int m = mb + j * 16 + lm;
      float4 g4 = *(const float4*)(gates + (size_t)m * 4);
      #pragma unroll
      for (int i = 0; i < 4; i++) {
        int n0 = dwc + i * 16 + q4;
        float4 bA = *(const float4*)&b2[0 * C_ + n0];
        float4 bB = *(const float4*)&b2[1 * C_ + n0];
        float4 bC = *(const float4*)&b2[2 * C_ + n0];
        float4 bD = *(const float4*)&b2[3 * C_ + n0];
        size_t idx = (size_t)m * C_ + n0;
        float4 r = *(const float4*)&x1[idx];
        float4 o;
        o.x = dacc[i][j][0]*sc + r.x + g4.x*bA.x + g4.y*bB.x + g4.z*bC.x + g4.w*bD.x;
        o.y = dacc[i][j][1]*sc + r.y + g4.x*bA.y + g4.y*bB.y + g4.z*bC.y + g4.w*bD.y;
        o.z = dacc[i][j][2]*sc + r.z + g4.x*bA.z + g4.y*bB.z + g4.z*bC.z + g4.w*bD.z;
        o.w = dacc[i][j][3]*sc + r.w + g4.x*bA.w + g4.y*bB.w + g4.z*bC.w + g4.w*bD.w;
        *(float4*)&out[idx] = o;
      }
    }
  }
}

extern "C" void kernel_launch(void* const* d_in, const int* in_sizes, int n_in,
                              void* d_out, int out_size, void* d_ws, size_t ws_size,
                              hipStream_t stream) {
  const float* x       = (const float*)d_in[0];
  const float* ln1_g   = (const float*)d_in[1];
  const float* ln1_b   = (const float*)d_in[2];
  const float* qkv_w   = (const float*)d_in[3];
  const float* qkv_b   = (const float*)d_in[4];
  const float* proj_w  = (const float*)d_in[5];
  const float* proj_b  = (const float*)d_in[6];
  const float* attn_g  = (const float*)d_in[7];
  const float* ln2_g   = (const float*)d_in[8];
  const float* ln2_b   = (const float*)d_in[9];
  const float* gat_w   = (const float*)d_in[10];
  const float* gat_b   = (const float*)d_in[11];
  const float* e_w1    = (const float*)d_in[12];
  const float* e_b1    = (const float*)d_in[13];
  const float* e_w2    = (const float*)d_in[14];
  const float* e_b2    = (const float*)d_in[15];
  float* out = (float*)d_out;

  char* p = (char*)d_ws;
  unsigned short* h    = (unsigned short*)p; p += (size_t)M_ * C_ * 2;      // 8 MB
  unsigned short* qkv  = (unsigned short*)p; p += (size_t)M_ * C3_ * 2;     // 24 MB
  unsigned short* Pb   = (unsigned short*)p; p += (size_t)M_ * C_ * 2;      // 8 MB
  unsigned short* aout = (unsigned short*)p; p += (size_t)M_ * C_ * 2;      // 8 MB
  float*          x1   = (float*)p;          p += (size_t)M_ * C_ * 4;      // 16 MB
  unsigned short* h2   = (unsigned short*)p; p += (size_t)M_ * C_ * 2;      // 8 MB
  float*          gts  = (float*)p;          p += (size_t)M_ * E_ * 4;      // 256 KB
  float*          S    = (float*)p;          p += (size_t)B_ * NCH_ * C_ * 4;
  unsigned short* wq   = (unsigned short*)p; p += (size_t)C3_ * C_ * 2;
  unsigned short* wp   = (unsigned short*)p; p += (size_t)C_ * C_ * 2;
  unsigned short* w1t  = (unsigned short*)p; p += (size_t)KH_ * C_ * 2;     // 2 MB [4096,256]
  unsigned char*  w2f8 = (unsigned char*)p;  p += (size_t)C_ * KH_;         // 1 MB blocked

  dim3 t32x8(32, 8);
  transpose_cvt<<<dim3(C3_/32, C_/32, 1), t32x8, 0, stream>>>(qkv_w, wq, C_, C3_, C_, 0);
  transpose_cvt<<<dim3(C_/32, C_/32, 1),  t32x8, 0, stream>>>(proj_w, wp, C_, C_, C_, 0);
  // w1t[e*1024 + hrow][c]  (flat [4096, 256]) bf16
  transpose_cvt<<<dim3(H_/32, C_/32, E_), t32x8, 0, stream>>>(e_w1, w1t, C_, H_, C_, (size_t)H_ * C_);
  // w2 -> fp8 x256, blocked [128 chunks][c][32] with granule swizzle
  transpose_w2_fp8<<<dim3(H_/32, C_/32, E_), t32x8, 0, stream>>>(e_w2, w2f8);

  ln1_kernel<<<M_, 256, 0, stream>>>(x, ln1_g, ln1_b, h);
  gemm128<0><<<dim3(M_/128, C3_/128), 256, 0, stream>>>(h, wq, qkv_b, C_, C3_,
      nullptr, nullptr, qkv);
  scan1_kernel<<<B_*NCH_, 256, 0, stream>>>(qkv, S);
  scan2_kernel<<<B_, 256, 0, stream>>>(S);
  scan3_kernel<<<B_*NCH_, 256, 0, stream>>>(qkv, S, Pb);
  attn_kernel<<<M_/4, 256, 0, stream>>>(qkv, Pb, attn_g, aout);
  // x1 = x + aout @ proj_w + proj_b
  gemm128<1><<<dim3(M_/128, C_/128), 256, 0, stream>>>(aout, wp, proj_b, C_, C_,
      x, x1, nullptr);
  ln2_gates_kernel<<<M_, 256, 0, stream>>>(x1, ln2_g, ln2_b, gat_w, gat_b, h2, gts);
  // fused MoE: 32-row blocks, grid 512 = 2 independent blocks/CU for phase overlap
  moe_fused<<<M_/32, 512, 0, stream>>>(h2, w1t, e_b1, w2f8, e_b2, gts, x1, out);
}

// Round 5
// 317.413 us; speedup vs baseline: 1.2557x; 1.0401x over previous
//
#include <hip/hip_runtime.h>
#include <hip/hip_bf16.h>
#include <math.h>

#define T_   4096
#define B_   4
#define C_   256
#define C3_  768
#define H_   1024
#define E_   4
#define M_   (B_*T_)      // 16384 rows
#define NCH_ 64
#define CHL_ (T_/NCH_)    // 64
#define KH_  4096         // E*H

typedef __attribute__((ext_vector_type(8))) short short8;
typedef __attribute__((ext_vector_type(4))) float floatx4;

__device__ __forceinline__ float b2f(unsigned short u) {
  union { unsigned int i; float f; } x; x.i = ((unsigned int)u) << 16; return x.f;
}
__device__ __forceinline__ unsigned short f2b(float f) {
  __hip_bfloat16 h = __float2bfloat16(f);
  return *reinterpret_cast<unsigned short*>(&h);
}
__device__ __forceinline__ void unpack8(uint4 a, float* f) {
  unsigned int w[4] = {a.x, a.y, a.z, a.w};
  #pragma unroll
  for (int i = 0; i < 4; i++) {
    union { unsigned int u; float g; } lo, hi;
    lo.u = w[i] << 16; hi.u = w[i] & 0xffff0000u;
    f[2*i] = lo.g; f[2*i+1] = hi.g;
  }
}
__device__ __forceinline__ void gl_lds16(const void* g, void* l) {
  __builtin_amdgcn_global_load_lds(
      (const __attribute__((address_space(1))) void*)g,
      (__attribute__((address_space(3))) void*)l, 16, 0, 0);
}
// sigmoid GELU: x*sigma(1.702x). |err|<=~0.01 on hid; attenuated by zero-mean w2 down-sum.
// Numerics verified on HW: passed with absmax 0.03125 using this form.
__device__ __forceinline__ float gelu_s(float v) {
  float e = __expf(-1.702f * v);
  return v * __builtin_amdgcn_rcpf(1.0f + e);
}
// pack 4 floats -> 4 fp8 e4m3 (OCP) in one uint
__device__ __forceinline__ unsigned int pk_fp8x4(float a, float b, float c, float d) {
  unsigned int v = 0;
  v = __builtin_amdgcn_cvt_pk_fp8_f32(a, b, v, false);
  v = __builtin_amdgcn_cvt_pk_fp8_f32(c, d, v, true);
  return v;
}
__device__ __forceinline__ unsigned char f2fp8(float v) {
  return (unsigned char)(__builtin_amdgcn_cvt_pk_fp8_f32(v, v, 0, false) & 0xff);
}
__device__ __forceinline__ float sel4(float4 v, int e) {
  float r = v.x;
  r = (e == 1) ? v.y : r;
  r = (e == 2) ? v.z : r;
  r = (e == 3) ? v.w : r;
  return r;
}

// ---------------- transpose + fp32->bf16: src[K,N](+z*K*N) -> dst[+z*zStr][n*dstLd + k] ----
__global__ __launch_bounds__(256) void transpose_cvt(
    const float* __restrict__ src, unsigned short* __restrict__ dst, int K, int N,
    int dstLd, size_t dstZStride) {
  __shared__ float tile[32][33];
  src += (size_t)blockIdx.z * K * N;
  dst += (size_t)blockIdx.z * dstZStride;
  int n0 = blockIdx.x * 32, k0 = blockIdx.y * 32;
  int tx = threadIdx.x, ty = threadIdx.y;   // blockDim (32,8)
  #pragma unroll
  for (int i = 0; i < 32; i += 8)
    tile[ty + i][tx] = src[(size_t)(k0 + ty + i) * N + n0 + tx];
  __syncthreads();
  #pragma unroll
  for (int i = 0; i < 32; i += 8)
    dst[(size_t)(n0 + ty + i) * dstLd + k0 + tx] = f2b(tile[tx][ty + i]);
}

// ---------------- w2 -> fp8 blocked: w2b[chunk=k>>6][c][64 bytes, seg-swizzled] ----------
// value = fp8(w2[e][h][c] * 256), k = e*1024+h.  Within the 64-byte row the 16B seg s
// is stored at s ^ ((c>>2)&3): down-GEMM b64 read bank = 16(c&1)+4(s^((c>>2)&3))+2(q&1)
// -> (c&1,(c>>2)&3) takes 8 distinct values over 16 lanes = 2-way (free).
// (old s^(c&3) gave 4-way: bank collapsed onto c&3 only.)
__global__ __launch_bounds__(256) void transpose_w2_fp8(
    const float* __restrict__ src, unsigned char* __restrict__ dst) {
  __shared__ float tile[32][33];
  int e = blockIdx.z;
  src += (size_t)e * H_ * C_;
  int h0 = blockIdx.x * 32, c0 = blockIdx.y * 32;
  int tx = threadIdx.x, ty = threadIdx.y;
  #pragma unroll
  for (int i = 0; i < 32; i += 8)
    tile[ty + i][tx] = src[(size_t)(h0 + ty + i) * C_ + c0 + tx];
  __syncthreads();
  int k = e * H_ + h0 + tx;
  int chunk = k >> 6, kc = k & 63;
  #pragma unroll
  for (int i = 0; i < 32; i += 8) {
    int c = c0 + ty + i;
    int sw = ((((kc >> 4) ^ ((c >> 2) & 3)) << 4) | (kc & 15));
    dst[((size_t)chunk * 256 + c) * 64 + sw] = f2fp8(tile[tx][ty + i] * 256.0f);
  }
}

// ---------------- LayerNorm 1 ----------------
__global__ __launch_bounds__(256) void ln1_kernel(
    const float* __restrict__ x, const float* __restrict__ g,
    const float* __restrict__ b, unsigned short* __restrict__ h) {
  __shared__ float red[4];
  int row = blockIdx.x, tid = threadIdx.x;
  float v = x[(size_t)row * C_ + tid];
  float s = v;
  #pragma unroll
  for (int o = 32; o; o >>= 1) s += __shfl_xor(s, o);
  if ((tid & 63) == 0) red[tid >> 6] = s;
  __syncthreads();
  float mean = (red[0] + red[1] + red[2] + red[3]) * (1.0f / C_);
  __syncthreads();
  float d = v - mean;
  float q = d * d;
  #pragma unroll
  for (int o = 32; o; o >>= 1) q += __shfl_xor(q, o);
  if ((tid & 63) == 0) red[tid >> 6] = q;
  __syncthreads();
  float var = (red[0] + red[1] + red[2] + red[3]) * (1.0f / C_);
  h[(size_t)row * C_ + tid] = f2b(d * rsqrtf(var + 1e-5f) * g[tid] + b[tid]);
}

// ---------------- LayerNorm 2 + gating softmax (h2 bf16) ----------------
__global__ __launch_bounds__(256) void ln2_gates_kernel(
    const float* __restrict__ x1, const float* __restrict__ g,
    const float* __restrict__ b, const float* __restrict__ gw,
    const float* __restrict__ gb, unsigned short* __restrict__ h2,
    float* __restrict__ gates) {
  __shared__ float red[4];
  __shared__ float redg[4][4];
  int row = blockIdx.x, tid = threadIdx.x;
  float v = x1[(size_t)row * C_ + tid];
  float s = v;
  #pragma unroll
  for (int o = 32; o; o >>= 1) s += __shfl_xor(s, o);
  if ((tid & 63) == 0) red[tid >> 6] = s;
  __syncthreads();
  float mean = (red[0] + red[1] + red[2] + red[3]) * (1.0f / C_);
  __syncthreads();
  float d = v - mean;
  float q = d * d;
  #pragma unroll
  for (int o = 32; o; o >>= 1) q += __shfl_xor(q, o);
  if ((tid & 63) == 0) red[tid >> 6] = q;
  __syncthreads();
  float var = (red[0] + red[1] + red[2] + red[3]) * (1.0f / C_);
  float hv = d * rsqrtf(var + 1e-5f) * g[tid] + b[tid];
  h2[(size_t)row * C_ + tid] = f2b(hv);
  float p0 = hv * gw[tid * 4 + 0];
  float p1 = hv * gw[tid * 4 + 1];
  float p2 = hv * gw[tid * 4 + 2];
  float p3 = hv * gw[tid * 4 + 3];
  #pragma unroll
  for (int o = 32; o; o >>= 1) {
    p0 += __shfl_xor(p0, o); p1 += __shfl_xor(p1, o);
    p2 += __shfl_xor(p2, o); p3 += __shfl_xor(p3, o);
  }
  if ((tid & 63) == 0) {
    int w = tid >> 6;
    redg[w][0] = p0; redg[w][1] = p1; redg[w][2] = p2; redg[w][3] = p3;
  }
  __syncthreads();
  if (tid == 0) {
    float t4[4];
    #pragma unroll
    for (int e = 0; e < 4; e++)
      t4[e] = redg[0][e] + redg[1][e] + redg[2][e] + redg[3][e] + gb[e];
    float m = fmaxf(fmaxf(t4[0], t4[1]), fmaxf(t4[2], t4[3]));
    float zs = 0.f;
    #pragma unroll
    for (int e = 0; e < 4; e++) { t4[e] = __expf(t4[e] - m); zs += t4[e]; }
    float inv = 1.0f / zs;
    #pragma unroll
    for (int e = 0; e < 4; e++) gates[(size_t)row * 4 + e] = t4[e] * inv;
  }
}

// ---------------- chunked prefix scan of v ----------------
__global__ __launch_bounds__(256) void scan1_kernel(const unsigned short* __restrict__ qkv,
                                                    float* __restrict__ S) {
  int b = blockIdx.x >> 6, ch = blockIdx.x & 63, c = threadIdx.x;
  float s = 0.f;
  size_t base = ((size_t)b * T_ + (size_t)ch * CHL_) * C3_ + 512 + c;
  for (int t = 0; t < CHL_; t++) s += b2f(qkv[base + (size_t)t * C3_]);
  S[((size_t)b * NCH_ + ch) * C_ + c] = s;
}
__global__ __launch_bounds__(256) void scan2_kernel(float* __restrict__ S) {
  int b = blockIdx.x, c = threadIdx.x;
  float run = 0.f;
  for (int ch = 0; ch < NCH_; ch++) {
    size_t i = ((size_t)b * NCH_ + ch) * C_ + c;
    float t = S[i]; S[i] = run; run += t;
  }
}
__global__ __launch_bounds__(256) void scan3_kernel(const unsigned short* __restrict__ qkv,
                                                    const float* __restrict__ S,
                                                    unsigned short* __restrict__ Pb) {
  int b = blockIdx.x >> 6, ch = blockIdx.x & 63, c = threadIdx.x;
  float run = S[((size_t)b * NCH_ + ch) * C_ + c];
  size_t row0 = (size_t)b * T_ + (size_t)ch * CHL_;
  for (int t = 0; t < CHL_; t++) {
    run += b2f(qkv[(row0 + t) * C3_ + 512 + c]);
    Pb[(row0 + t) * C_ + c] = f2b(run);
  }
}

// ---------------- windowed attention: 16-lane group per window position ----------------
__global__ __launch_bounds__(256) void attn_kernel(
    const unsigned short* __restrict__ qkv, const unsigned short* __restrict__ Pb,
    const float* __restrict__ gate, unsigned short* __restrict__ aout) {
  int wave = threadIdx.x >> 6, lane = threadIdx.x & 63;
  int r = blockIdx.x * 4 + wave;
  int t = r & (T_ - 1);
  int g = lane >> 4, u = lane & 15;
  const unsigned short* qp = qkv + (size_t)r * C3_ + (u << 4);
  float qv[16];
  unpack8(*(const uint4*)qp, qv);
  unpack8(*(const uint4*)(qp + 8), qv + 8);
  float sc[5];
  #pragma unroll
  for (int rnd = 0; rnd < 5; rnd++) {
    int j = rnd * 4 + g;
    int jj = t - 16 + j;
    bool valid = (j <= 16) && (jj >= 0);
    float d = 0.f;
    if (valid) {
      const unsigned short* kp = qkv + (size_t)(r - 16 + j) * C3_ + 256 + (u << 4);
      float kv[16];
      unpack8(*(const uint4*)kp, kv);
      unpack8(*(const uint4*)(kp + 8), kv + 8);
      #pragma unroll
      for (int c = 0; c < 16; c++) d += qv[c] * kv[c];
    }
    d += __shfl_xor(d, 1); d += __shfl_xor(d, 2);
    d += __shfl_xor(d, 4); d += __shfl_xor(d, 8);
    sc[rnd] = valid ? d * 0.0625f : -1e30f;
  }
  float m = fmaxf(fmaxf(fmaxf(sc[0], sc[1]), fmaxf(sc[2], sc[3])), sc[4]);
  m = fmaxf(m, __shfl_xor(m, 16));
  m = fmaxf(m, __shfl_xor(m, 32));
  if (t > 16) m = fmaxf(m, 0.0f);
  float ev[5], Zp = 0.f;
  #pragma unroll
  for (int rnd = 0; rnd < 5; rnd++) {
    ev[rnd] = (sc[rnd] > -1e29f) ? __expf(sc[rnd] - m) : 0.f;
    Zp += ev[rnd];
  }
  Zp += __shfl_xor(Zp, 16);
  Zp += __shfl_xor(Zp, 32);
  float e0v = 0.f;
  if (t > 16) { e0v = __expf(-m); Zp += e0v * (float)(t - 16); }
  float vp[16];
  #pragma unroll
  for (int c = 0; c < 16; c++) vp[c] = 0.f;
  #pragma unroll
  for (int rnd = 0; rnd < 5; rnd++) {
    if (ev[rnd] != 0.f) {
      int j = rnd * 4 + g;
      const unsigned short* vpp = qkv + (size_t)(r - 16 + j) * C3_ + 512 + (u << 4);
      float vv[16];
      unpack8(*(const uint4*)vpp, vv);
      unpack8(*(const uint4*)(vpp + 8), vv + 8);
      #pragma unroll
      for (int c = 0; c < 16; c++) vp[c] += ev[rnd] * vv[c];
    }
  }
  #pragma unroll
  for (int c = 0; c < 16; c++) {
    vp[c] += __shfl_xor(vp[c], 16);
    vp[c] += __shfl_xor(vp[c], 32);
  }
  if (g == 0) {
    if (t > 16) {
      const unsigned short* pp = Pb + (size_t)(r - 17) * C_ + (u << 4);
      float pv[16];
      unpack8(*(const uint4*)pp, pv);
      unpack8(*(const uint4*)(pp + 8), pv + 8);
      #pragma unroll
      for (int c = 0; c < 16; c++) vp[c] += e0v * pv[c];
    }
    float inv = 1.0f / Zp;
    const float* gp = gate + (u << 4);
    unsigned int ow[8];
    #pragma unroll
    for (int i = 0; i < 8; i++) {
      unsigned short lo = f2b(vp[2*i] * inv * gp[2*i]);
      unsigned short hi = f2b(vp[2*i+1] * inv * gp[2*i+1]);
      ow[i] = (unsigned int)lo | ((unsigned int)hi << 16);
    }
    uint4 s0 = {ow[0], ow[1], ow[2], ow[3]};
    uint4 s1 = {ow[4], ow[5], ow[6], ow[7]};
    *(uint4*)(aout + (size_t)r * C_ + (u << 4)) = s0;
    *(uint4*)(aout + (size_t)r * C_ + (u << 4) + 8) = s1;
  }
}

// ---------------- 128x128 MFMA GEMM, operand-swapped, swizzled staging ------------------
// EPI 0: outb = bf16(acc + bias)                              (qkv)
// EPI 1: x1 = acc + bias + resid                              (proj)
template<int EPI>
__global__ __launch_bounds__(256) void gemm128(
    const unsigned short* __restrict__ A, const unsigned short* __restrict__ Bt,
    const float* __restrict__ bias, int K, int ldOut,
    const float* __restrict__ resid, float* __restrict__ outf,
    unsigned short* __restrict__ outb) {
  __shared__ __align__(16) unsigned short As[128 * 64];
  __shared__ __align__(16) unsigned short Bs[128 * 64];
  const int tid = threadIdx.x;
  const int wave = tid >> 6, lane = tid & 63;
  const int mBlk = blockIdx.x * 128, nBlk = blockIdx.y * 128;
  const int wm = (wave >> 1) * 64, wn = (wave & 1) * 64;
  const int lm = lane & 15, lk = (lane >> 4) * 8;
  floatx4 acc[4][4];
  #pragma unroll
  for (int i = 0; i < 4; i++)
    #pragma unroll
    for (int j = 0; j < 4; j++) acc[i][j] = (floatx4){0.f, 0.f, 0.f, 0.f};

  for (int kt = 0; kt < K; kt += 64) {
    __syncthreads();
    #pragma unroll
    for (int i = 0; i < 4; i++) {
      int seg = i * 256 + tid;          // 16B segment index
      int row = seg >> 3, g = seg & 7;
      int gc = (g ^ (row & 7)) << 3;    // XOR-swizzle the GLOBAL column (LDS stays linear)
      gl_lds16(A + (size_t)(mBlk + row) * K + kt + gc, &As[seg * 8]);
      gl_lds16(Bt + (size_t)(nBlk + row) * K + kt + gc, &Bs[seg * 8]);
    }
    __syncthreads();
    #pragma unroll
    for (int kk = 0; kk < 64; kk += 32) {
      short8 mf[4], nf[4];
      #pragma unroll
      for (int j = 0; j < 4; j++) {
        int row = wm + j * 16 + lm;
        mf[j] = *(const short8*)&As[row * 64 + ((((kk + lk) >> 3) ^ (row & 7)) << 3)];
      }
      #pragma unroll
      for (int i = 0; i < 4; i++) {
        int row = wn + i * 16 + lm;
        nf[i] = *(const short8*)&Bs[row * 64 + ((((kk + lk) >> 3) ^ (row & 7)) << 3)];
      }
      #pragma unroll
      for (int i = 0; i < 4; i++)
        #pragma unroll
        for (int j = 0; j < 4; j++)
          acc[i][j] = __builtin_amdgcn_mfma_f32_16x16x32_bf16(nf[i], mf[j], acc[i][j], 0, 0, 0);
    }
  }
  const int lc = lane & 15, quad = lane >> 4, q4 = quad * 4;
  #pragma unroll
  for (int i = 0; i < 4; i++) {
    int n0 = nBlk + wn + i * 16 + q4;
    float4 bs = *(const float4*)&bias[n0];
    #pragma unroll
    for (int j = 0; j < 4; j++) {
      int m = mBlk + wm + j * 16 + lc;
      float v0 = acc[i][j][0] + bs.x, v1 = acc[i][j][1] + bs.y;
      float v2 = acc[i][j][2] + bs.z, v3 = acc[i][j][3] + bs.w;
      if (EPI == 0) {
        ushort4 o = {f2b(v0), f2b(v1), f2b(v2), f2b(v3)};
        *(ushort4*)&outb[(size_t)m * ldOut + n0] = o;
      } else {
        size_t idx = (size_t)m * ldOut + n0;
        float4 r = *(const float4*)&resid[idx];
        float4 o = {v0 + r.x, v1 + r.y, v2 + r.z, v3 + r.w};
        *(float4*)&outf[idx] = o;
      }
    }
  }
}

// ---------------- fused MoE, producer/consumer wave split (R2 structure) ----------------
// 512 threads: waves 0-3 = up (h2@w1 + gelu + fp8 -> Hs), waves 4-7 = down (Hs@w2 -> dacc).
// Down lags up by one chunk (Hs double-buffered). Per iteration: B1 (everyone finished
// chunk c-1 -> buffer overwrite + Hs publish safe), vmcnt(0) (prev-iter stages landed,
// near-free since issued one compute-phase ago), B2 (cross-wave visibility), THEN stage
// issue overlapped with compute (DMA issue off the serial path). W2 seg-swizzle
// ((c>>2)-based) makes the down b64 reads 2-way (free) instead of 4-way.
__global__ __launch_bounds__(512, 2) void moe_fused(
    const unsigned short* __restrict__ h2,   // [M,256] bf16
    const unsigned short* __restrict__ w1t,  // [4096,256] bf16
    const float* __restrict__ b1,            // [4096] flat
    const unsigned char* __restrict__ w2b,   // [64][256][64] fp8 (x256, seg-swizzled)
    const float* __restrict__ b2,            // [4][256]
    const float* __restrict__ gates,         // [M,4]
    const float* __restrict__ x1,            // [M,256]
    float* __restrict__ out) {
  __shared__ __align__(16) unsigned short W1s[2][64 * 256];    // 64 KB
  __shared__ __align__(16) unsigned char  W2s[2][256 * 64];    // 32 KB
  __shared__ __align__(16) unsigned char  Hs[2][64 * 64];      // 8 KB
  __shared__ __align__(16) float          B1s[2][64];          // 512 B
  const int tid = threadIdx.x;
  const int wave = tid >> 6, lane = tid & 63;
  const int lm = lane & 15, quad = lane >> 4;
  const int mb = blockIdx.x * 64;
  const bool isUp = wave < 4;
  const int uw = wave & 3;
  const int wmu = (uw >> 1) * 32;     // up-tile m offset
  const int whu = (uw & 1) * 32;      // up-tile h offset
  const int wc  = uw * 64;            // down-tile c offset

  // stage W1 chunk c + b1 slice into buffer buf: 5 vmem instrs/wave
  auto stageW1 = [&](int c, int buf) {
    const unsigned short* ws = w1t + (size_t)c * 64 * C_;
    #pragma unroll
    for (int t = 0; t < 4; t++) {
      int seg = t * 512 + tid;
      int row = seg >> 5, g = seg & 31;
      int gp = (g & 24) | ((g & 7) ^ (row & 7));
      gl_lds16(ws + (size_t)row * C_ + gp * 8, &W1s[buf][seg * 8]);
    }
    if (lane < 16)
      gl_lds16(b1 + (size_t)c * 64 + lane * 4, &B1s[buf][0]);
  };
  // stage W2 chunk c into buffer buf: 2 vmem instrs/wave (pre-blocked linear 16 KB)
  auto stageW2 = [&](int c, int buf) {
    const unsigned char* vs = w2b + (size_t)c * 256 * 64;
    #pragma unroll
    for (int t = 0; t < 2; t++) {
      int seg = t * 512 + tid;
      gl_lds16(vs + (size_t)seg * 16, &W2s[buf][seg * 16]);
    }
  };

  stageW1(0, 0);

  // A-fragments -> registers (up waves): h2 rows [mb+wmu, +32), read once, reused 64 chunks
  short8 af[8][2];
  float4 ga[2];
  if (isUp) {
    #pragma unroll
    for (int kk = 0; kk < 8; kk++) {
      int kc = kk * 4 + quad;
      #pragma unroll
      for (int j = 0; j < 2; j++) {
        int row = mb + wmu + j * 16 + lm;
        af[kk][j] = *(const short8*)(h2 + (size_t)row * C_ + kc * 8);
      }
    }
    #pragma unroll
    for (int j = 0; j < 2; j++)
      ga[j] = *(const float4*)(gates + (size_t)(mb + wmu + j * 16 + lm) * 4);
  }

  floatx4 dacc[4][4];   // [i = c-frag][j = m-frag], down waves only
  #pragma unroll
  for (int i = 0; i < 4; i++)
    #pragma unroll
    for (int j = 0; j < 4; j++) dacc[i][j] = (floatx4){0.f, 0.f, 0.f, 0.f};

  for (int c = 0; c < 64; c++) {
    const int wb = c & 1;
    // (B1): everyone finished iter c-1 -> safe to overwrite W1s[wb^1]/W2s[wb]; Hs[wb^1]
    // writes (lgkm'd before arrival) are publishable
    __builtin_amdgcn_s_barrier();
    __builtin_amdgcn_sched_barrier(0);
    asm volatile("s_waitcnt vmcnt(0)" ::: "memory");   // my prev-iter loads landed (cheap)
    // (B2): all waves' chunk-c staging visible
    __builtin_amdgcn_s_barrier();
    __builtin_amdgcn_sched_barrier(0);
    // stage issue AFTER the barriers: DMA issue overlaps compute below
    stageW1((c + 1) & 63, wb ^ 1);     // W1/b1 for chunk c+1 (wrap harmless)
    stageW2(c, wb);                    // W2 for chunk c (consumed next iter)

    if (isUp) {
      // ---- up-GEMM chunk c: uacc = h2[32m] x w1[32h], K=256
      floatx4 uacc[2][2];
      #pragma unroll
      for (int i = 0; i < 2; i++)
        #pragma unroll
        for (int j = 0; j < 2; j++) uacc[i][j] = (floatx4){0.f, 0.f, 0.f, 0.f};
      #pragma unroll
      for (int kk = 0; kk < 8; kk++) {
        int kc = kk * 4 + quad;
        short8 nf[2];
        #pragma unroll
        for (int i = 0; i < 2; i++) {
          int row = whu + i * 16 + lm;
          nf[i] = *(const short8*)&W1s[wb][row * 256 + ((kc ^ (row & 7)) << 3)];
        }
        #pragma unroll
        for (int i = 0; i < 2; i++)
          #pragma unroll
          for (int j = 0; j < 2; j++)
            uacc[i][j] = __builtin_amdgcn_mfma_f32_16x16x32_bf16(nf[i], af[kk][j], uacc[i][j], 0, 0, 0);
      }
      // ---- gelu + gate + fp8 -> Hs[wb], XOR-swizzled 8B granules
      int e = c >> 4;
      float gs0 = 64.0f * sel4(ga[0], e);
      float gs1 = 64.0f * sel4(ga[1], e);
      #pragma unroll
      for (int i = 0; i < 2; i++) {
        float4 bb = *(const float4*)&B1s[wb][whu + i * 16 + quad * 4];
        #pragma unroll
        for (int j = 0; j < 2; j++) {
          float gs = j ? gs1 : gs0;
          unsigned int w = pk_fp8x4(gs * gelu_s(uacc[i][j][0] + bb.x),
                                    gs * gelu_s(uacc[i][j][1] + bb.y),
                                    gs * gelu_s(uacc[i][j][2] + bb.z),
                                    gs * gelu_s(uacc[i][j][3] + bb.w));
          int m = wmu + j * 16 + lm;
          int hh = whu + i * 16 + quad * 4;
          *(unsigned int*)&Hs[wb][m * 64 + ((((hh >> 3) ^ (m & 7)) << 3) | (hh & 7))] = w;
        }
      }
      asm volatile("s_waitcnt lgkmcnt(0)" ::: "memory");   // Hs writes landed before B1
    } else if (c > 0) {
      // ---- down-GEMM chunk c-1: dacc += hid8[64m x 64k] x w2[64c x 64k] (fp8)
      const int pb = wb ^ 1;
      #pragma unroll
      for (int kk = 0; kk < 2; kk++) {
        long mfh[4], nfw[4];
        #pragma unroll
        for (int j = 0; j < 4; j++) {
          int m = j * 16 + lm;
          int g8 = quad + 4 * kk;
          mfh[j] = *(const long*)&Hs[pb][m * 64 + ((g8 ^ (m & 7)) << 3)];
        }
        #pragma unroll
        for (int i = 0; i < 4; i++) {
          int cr = wc + i * 16 + lm;
          int sl = ((quad >> 1) + 2 * kk) ^ ((cr >> 2) & 3);
          nfw[i] = *(const long*)&W2s[pb][cr * 64 + (sl << 4) + ((quad & 1) << 3)];
        }
        #pragma unroll
        for (int i = 0; i < 4; i++)
          #pragma unroll
          for (int j = 0; j < 4; j++)
            dacc[i][j] = __builtin_amdgcn_mfma_f32_16x16x32_fp8_fp8(nfw[i], mfh[j], dacc[i][j], 0, 0, 0);
      }
    }
  }

  // ---- drain: final down step for chunk 63 (Hs[1], W2s[1]), then epilogue
  asm volatile("s_waitcnt vmcnt(0)" ::: "memory");
  __builtin_amdgcn_s_barrier();
  __builtin_amdgcn_sched_barrier(0);
  if (!isUp) {
    #pragma unroll
    for (int kk = 0; kk < 2; kk++) {
      long mfh[4], nfw[4];
      #pragma unroll
      for (int j = 0; j < 4; j++) {
        int m = j * 16 + lm;
        int g8 = quad + 4 * kk;
        mfh[j] = *(const long*)&Hs[1][m * 64 + ((g8 ^ (m & 7)) << 3)];
      }
      #pragma unroll
      for (int i = 0; i < 4; i++) {
        int cr = wc + i * 16 + lm;
        int sl = ((quad >> 1) + 2 * kk) ^ ((cr >> 2) & 3);
        nfw[i] = *(const long*)&W2s[1][cr * 64 + (sl << 4) + ((quad & 1) << 3)];
      }
      #pragma unroll
      for (int i = 0; i < 4; i++)
        #pragma unroll
        for (int j = 0; j < 4; j++)
          dacc[i][j] = __builtin_amdgcn_mfma_f32_16x16x32_fp8_fp8(nfw[i], mfh[j], dacc[i][j], 0, 0, 0);
    }
    // ---- epilogue: out = dacc/2^14 + x1 + sum_e gate_e * b2_e
    const float sc = 1.0f / 16384.0f;
    const int q4 = quad * 4;
    #pragma unroll
    for (int j = 0; j < 4; j++) {
      int m = mb + j * 16 + lm;
      float4 g4 = *(const float4*)(gates + (size_t)m * 4);
      #pragma unroll
      for (int i = 0; i < 4; i++) {
        int n0 = wc + i * 16 + q4;
        float4 bA = *(const float4*)&b2[0 * C_ + n0];
        float4 bB = *(const float4*)&b2[1 * C_ + n0];
        float4 bC = *(const float4*)&b2[2 * C_ + n0];
        float4 bD = *(const float4*)&b2[3 * C_ + n0];
        size_t idx = (size_t)m * C_ + n0;
        float4 r = *(const float4*)&x1[idx];
        float4 o;
        o.x = dacc[i][j][0]*sc + r.x + g4.x*bA.x + g4.y*bB.x + g4.z*bC.x + g4.w*bD.x;
        o.y = dacc[i][j][1]*sc + r.y + g4.x*bA.y + g4.y*bB.y + g4.z*bC.y + g4.w*bD.y;
        o.z = dacc[i][j][2]*sc + r.z + g4.x*bA.z + g4.y*bB.z + g4.z*bC.z + g4.w*bD.z;
        o.w = dacc[i][j][3]*sc + r.w + g4.x*bA.w + g4.y*bB.w + g4.z*bC.w + g4.w*bD.w;
        *(float4*)&out[idx] = o;
      }
    }
  }
}

extern "C" void kernel_launch(void* const* d_in, const int* in_sizes, int n_in,
                              void* d_out, int out_size, void* d_ws, size_t ws_size,
                              hipStream_t stream) {
  const float* x       = (const float*)d_in[0];
  const float* ln1_g   = (const float*)d_in[1];
  const float* ln1_b   = (const float*)d_in[2];
  const float* qkv_w   = (const float*)d_in[3];
  const float* qkv_b   = (const float*)d_in[4];
  const float* proj_w  = (const float*)d_in[5];
  const float* proj_b  = (const float*)d_in[6];
  const float* attn_g  = (const float*)d_in[7];
  const float* ln2_g   = (const float*)d_in[8];
  const float* ln2_b   = (const float*)d_in[9];
  const float* gat_w   = (const float*)d_in[10];
  const float* gat_b   = (const float*)d_in[11];
  const float* e_w1    = (const float*)d_in[12];
  const float* e_b1    = (const float*)d_in[13];
  const float* e_w2    = (const float*)d_in[14];
  const float* e_b2    = (const float*)d_in[15];
  float* out = (float*)d_out;

  char* p = (char*)d_ws;
  unsigned short* h    = (unsigned short*)p; p += (size_t)M_ * C_ * 2;      // 8 MB
  unsigned short* qkv  = (unsigned short*)p; p += (size_t)M_ * C3_ * 2;     // 24 MB
  unsigned short* Pb   = (unsigned short*)p; p += (size_t)M_ * C_ * 2;      // 8 MB
  unsigned short* aout = (unsigned short*)p; p += (size_t)M_ * C_ * 2;      // 8 MB
  float*          x1   = (float*)p;          p += (size_t)M_ * C_ * 4;      // 16 MB
  unsigned short* h2   = (unsigned short*)p; p += (size_t)M_ * C_ * 2;      // 8 MB
  float*          gts  = (float*)p;          p += (size_t)M_ * E_ * 4;      // 256 KB
  float*          S    = (float*)p;          p += (size_t)B_ * NCH_ * C_ * 4;
  unsigned short* wq   = (unsigned short*)p; p += (size_t)C3_ * C_ * 2;
  unsigned short* wp   = (unsigned short*)p; p += (size_t)C_ * C_ * 2;
  unsigned short* w1t  = (unsigned short*)p; p += (size_t)KH_ * C_ * 2;     // 2 MB [4096,256]
  unsigned char*  w2f8 = (unsigned char*)p;  p += (size_t)C_ * KH_;         // 1 MB blocked

  dim3 t32x8(32, 8);
  transpose_cvt<<<dim3(C3_/32, C_/32, 1), t32x8, 0, stream>>>(qkv_w, wq, C_, C3_, C_, 0);
  transpose_cvt<<<dim3(C_/32, C_/32, 1),  t32x8, 0, stream>>>(proj_w, wp, C_, C_, C_, 0);
  // w1t[e*1024 + hrow][c]  (flat [4096, 256]) bf16
  transpose_cvt<<<dim3(H_/32, C_/32, E_), t32x8, 0, stream>>>(e_w1, w1t, C_, H_, C_, (size_t)H_ * C_);
  // w2 -> fp8 x256, blocked [64 chunks][c][64] with (c>>2) seg swizzle
  transpose_w2_fp8<<<dim3(H_/32, C_/32, E_), t32x8, 0, stream>>>(e_w2, w2f8);

  ln1_kernel<<<M_, 256, 0, stream>>>(x, ln1_g, ln1_b, h);
  gemm128<0><<<dim3(M_/128, C3_/128), 256, 0, stream>>>(h, wq, qkv_b, C_, C3_,
      nullptr, nullptr, qkv);
  scan1_kernel<<<B_*NCH_, 256, 0, stream>>>(qkv, S);
  scan2_kernel<<<B_, 256, 0, stream>>>(S);
  scan3_kernel<<<B_*NCH_, 256, 0, stream>>>(qkv, S, Pb);
  attn_kernel<<<M_/4, 256, 0, stream>>>(qkv, Pb, attn_g, aout);
  // x1 = x + aout @ proj_w + proj_b
  gemm128<1><<<dim3(M_/128, C_/128), 256, 0, stream>>>(aout, wp, proj_b, C_, C_,
      x, x1, nullptr);
  ln2_gates_kernel<<<M_, 256, 0, stream>>>(x1, ln2_g, ln2_b, gat_w, gat_b, h2, gts);
  // fused MoE: producer waves (up+gelu+fp8) || consumer waves (down), Hs double-buffered
  moe_fused<<<M_/64, 512, 0, stream>>>(h2, w1t, e_b1, w2f8, e_b2, gts, x1, out);
}

// Round 7
// 317.322 us; speedup vs baseline: 1.2560x; 1.0003x over previous
//
#include <hip/hip_runtime.h>
#include <hip/hip_bf16.h>
#include <math.h>

#define T_   4096
#define B_   4
#define C_   256
#define C3_  768
#define H_   1024
#define E_   4
#define M_   (B_*T_)      // 16384 rows
#define NCH_ 64
#define CHL_ (T_/NCH_)    // 64
#define KH_  4096         // E*H

typedef __attribute__((ext_vector_type(8))) short short8;
typedef __attribute__((ext_vector_type(4))) float floatx4;

__device__ __forceinline__ float b2f(unsigned short u) {
  union { unsigned int i; float f; } x; x.i = ((unsigned int)u) << 16; return x.f;
}
__device__ __forceinline__ unsigned short f2b(float f) {
  __hip_bfloat16 h = __float2bfloat16(f);
  return *reinterpret_cast<unsigned short*>(&h);
}
__device__ __forceinline__ void unpack8(uint4 a, float* f) {
  unsigned int w[4] = {a.x, a.y, a.z, a.w};
  #pragma unroll
  for (int i = 0; i < 4; i++) {
    union { unsigned int u; float g; } lo, hi;
    lo.u = w[i] << 16; hi.u = w[i] & 0xffff0000u;
    f[2*i] = lo.g; f[2*i+1] = hi.g;
  }
}
__device__ __forceinline__ void gl_lds16(const void* g, void* l) {
  __builtin_amdgcn_global_load_lds(
      (const __attribute__((address_space(1))) void*)g,
      (__attribute__((address_space(3))) void*)l, 16, 0, 0);
}
// sigmoid GELU: x*sigma(1.702x). |err|<=~0.01 on hid; attenuated by zero-mean w2 down-sum.
// Numerics verified on HW: passed with absmax 0.03125 using this form.
__device__ __forceinline__ float gelu_s(float v) {
  float e = __expf(-1.702f * v);
  return v * __builtin_amdgcn_rcpf(1.0f + e);
}
// pack 4 floats -> 4 fp8 e4m3 (OCP) in one uint
__device__ __forceinline__ unsigned int pk_fp8x4(float a, float b, float c, float d) {
  unsigned int v = 0;
  v = __builtin_amdgcn_cvt_pk_fp8_f32(a, b, v, false);
  v = __builtin_amdgcn_cvt_pk_fp8_f32(c, d, v, true);
  return v;
}
__device__ __forceinline__ unsigned char f2fp8(float v) {
  return (unsigned char)(__builtin_amdgcn_cvt_pk_fp8_f32(v, v, 0, false) & 0xff);
}
__device__ __forceinline__ float sel4(float4 v, int e) {
  float r = v.x;
  r = (e == 1) ? v.y : r;
  r = (e == 2) ? v.z : r;
  r = (e == 3) ? v.w : r;
  return r;
}

// ---------------- transpose + fp32->bf16: src[K,N](+z*K*N) -> dst[+z*zStr][n*dstLd + k] ----
__global__ __launch_bounds__(256) void transpose_cvt(
    const float* __restrict__ src, unsigned short* __restrict__ dst, int K, int N,
    int dstLd, size_t dstZStride) {
  __shared__ float tile[32][33];
  src += (size_t)blockIdx.z * K * N;
  dst += (size_t)blockIdx.z * dstZStride;
  int n0 = blockIdx.x * 32, k0 = blockIdx.y * 32;
  int tx = threadIdx.x, ty = threadIdx.y;   // blockDim (32,8)
  #pragma unroll
  for (int i = 0; i < 32; i += 8)
    tile[ty + i][tx] = src[(size_t)(k0 + ty + i) * N + n0 + tx];
  __syncthreads();
  #pragma unroll
  for (int i = 0; i < 32; i += 8)
    dst[(size_t)(n0 + ty + i) * dstLd + k0 + tx] = f2b(tile[tx][ty + i]);
}

// ---------------- w2 -> fp8 blocked: w2b[chunk=k>>6][c][64 bytes, seg-swizzled] ----------
// value = fp8(w2[e][h][c] * 256), k = e*1024+h.  Within the 64-byte row the 16B seg s
// is stored at s ^ ((c>>2)&3): down-GEMM b64 read bank = 16(c&1)+4(s^((c>>2)&3))+2(q&1)
// -> (c&1,(c>>2)&3) takes 8 distinct values over 16 lanes = 2-way (free).
__global__ __launch_bounds__(256) void transpose_w2_fp8(
    const float* __restrict__ src, unsigned char* __restrict__ dst) {
  __shared__ float tile[32][33];
  int e = blockIdx.z;
  src += (size_t)e * H_ * C_;
  int h0 = blockIdx.x * 32, c0 = blockIdx.y * 32;
  int tx = threadIdx.x, ty = threadIdx.y;
  #pragma unroll
  for (int i = 0; i < 32; i += 8)
    tile[ty + i][tx] = src[(size_t)(h0 + ty + i) * C_ + c0 + tx];
  __syncthreads();
  int k = e * H_ + h0 + tx;
  int chunk = k >> 6, kc = k & 63;
  #pragma unroll
  for (int i = 0; i < 32; i += 8) {
    int c = c0 + ty + i;
    int sw = ((((kc >> 4) ^ ((c >> 2) & 3)) << 4) | (kc & 15));
    dst[((size_t)chunk * 256 + c) * 64 + sw] = f2fp8(tile[tx][ty + i] * 256.0f);
  }
}

// ---------------- LayerNorm 1 ----------------
__global__ __launch_bounds__(256) void ln1_kernel(
    const float* __restrict__ x, const float* __restrict__ g,
    const float* __restrict__ b, unsigned short* __restrict__ h) {
  __shared__ float red[4];
  int row = blockIdx.x, tid = threadIdx.x;
  float v = x[(size_t)row * C_ + tid];
  float s = v;
  #pragma unroll
  for (int o = 32; o; o >>= 1) s += __shfl_xor(s, o);
  if ((tid & 63) == 0) red[tid >> 6] = s;
  __syncthreads();
  float mean = (red[0] + red[1] + red[2] + red[3]) * (1.0f / C_);
  __syncthreads();
  float d = v - mean;
  float q = d * d;
  #pragma unroll
  for (int o = 32; o; o >>= 1) q += __shfl_xor(q, o);
  if ((tid & 63) == 0) red[tid >> 6] = q;
  __syncthreads();
  float var = (red[0] + red[1] + red[2] + red[3]) * (1.0f / C_);
  h[(size_t)row * C_ + tid] = f2b(d * rsqrtf(var + 1e-5f) * g[tid] + b[tid]);
}

// ---------------- LayerNorm 2 + gating softmax (h2 bf16) ----------------
__global__ __launch_bounds__(256) void ln2_gates_kernel(
    const float* __restrict__ x1, const float* __restrict__ g,
    const float* __restrict__ b, const float* __restrict__ gw,
    const float* __restrict__ gb, unsigned short* __restrict__ h2,
    float* __restrict__ gates) {
  __shared__ float red[4];
  __shared__ float redg[4][4];
  int row = blockIdx.x, tid = threadIdx.x;
  float v = x1[(size_t)row * C_ + tid];
  float s = v;
  #pragma unroll
  for (int o = 32; o; o >>= 1) s += __shfl_xor(s, o);
  if ((tid & 63) == 0) red[tid >> 6] = s;
  __syncthreads();
  float mean = (red[0] + red[1] + red[2] + red[3]) * (1.0f / C_);
  __syncthreads();
  float d = v - mean;
  float q = d * d;
  #pragma unroll
  for (int o = 32; o; o >>= 1) q += __shfl_xor(q, o);
  if ((tid & 63) == 0) red[tid >> 6] = q;
  __syncthreads();
  float var = (red[0] + red[1] + red[2] + red[3]) * (1.0f / C_);
  float hv = d * rsqrtf(var + 1e-5f) * g[tid] + b[tid];
  h2[(size_t)row * C_ + tid] = f2b(hv);
  float p0 = hv * gw[tid * 4 + 0];
  float p1 = hv * gw[tid * 4 + 1];
  float p2 = hv * gw[tid * 4 + 2];
  float p3 = hv * gw[tid * 4 + 3];
  #pragma unroll
  for (int o = 32; o; o >>= 1) {
    p0 += __shfl_xor(p0, o); p1 += __shfl_xor(p1, o);
    p2 += __shfl_xor(p2, o); p3 += __shfl_xor(p3, o);
  }
  if ((tid & 63) == 0) {
    int w = tid >> 6;
    redg[w][0] = p0; redg[w][1] = p1; redg[w][2] = p2; redg[w][3] = p3;
  }
  __syncthreads();
  if (tid == 0) {
    float t4[4];
    #pragma unroll
    for (int e = 0; e < 4; e++)
      t4[e] = redg[0][e] + redg[1][e] + redg[2][e] + redg[3][e] + gb[e];
    float m = fmaxf(fmaxf(t4[0], t4[1]), fmaxf(t4[2], t4[3]));
    float zs = 0.f;
    #pragma unroll
    for (int e = 0; e < 4; e++) { t4[e] = __expf(t4[e] - m); zs += t4[e]; }
    float inv = 1.0f / zs;
    #pragma unroll
    for (int e = 0; e < 4; e++) gates[(size_t)row * 4 + e] = t4[e] * inv;
  }
}

// ---------------- chunked prefix scan of v ----------------
__global__ __launch_bounds__(256) void scan1_kernel(const unsigned short* __restrict__ qkv,
                                                    float* __restrict__ S) {
  int b = blockIdx.x >> 6, ch = blockIdx.x & 63, c = threadIdx.x;
  float s = 0.f;
  size_t base = ((size_t)b * T_ + (size_t)ch * CHL_) * C3_ + 512 + c;
  for (int t = 0; t < CHL_; t++) s += b2f(qkv[base + (size_t)t * C3_]);
  S[((size_t)b * NCH_ + ch) * C_ + c] = s;
}
__global__ __launch_bounds__(256) void scan2_kernel(float* __restrict__ S) {
  int b = blockIdx.x, c = threadIdx.x;
  float run = 0.f;
  for (int ch = 0; ch < NCH_; ch++) {
    size_t i = ((size_t)b * NCH_ + ch) * C_ + c;
    float t = S[i]; S[i] = run; run += t;
  }
}
__global__ __launch_bounds__(256) void scan3_kernel(const unsigned short* __restrict__ qkv,
                                                    const float* __restrict__ S,
                                                    unsigned short* __restrict__ Pb) {
  int b = blockIdx.x >> 6, ch = blockIdx.x & 63, c = threadIdx.x;
  float run = S[((size_t)b * NCH_ + ch) * C_ + c];
  size_t row0 = (size_t)b * T_ + (size_t)ch * CHL_;
  for (int t = 0; t < CHL_; t++) {
    run += b2f(qkv[(row0 + t) * C3_ + 512 + c]);
    Pb[(row0 + t) * C_ + c] = f2b(run);
  }
}

// ---------------- windowed attention: 16-lane group per window position ----------------
__global__ __launch_bounds__(256) void attn_kernel(
    const unsigned short* __restrict__ qkv, const unsigned short* __restrict__ Pb,
    const float* __restrict__ gate, unsigned short* __restrict__ aout) {
  int wave = threadIdx.x >> 6, lane = threadIdx.x & 63;
  int r = blockIdx.x * 4 + wave;
  int t = r & (T_ - 1);
  int g = lane >> 4, u = lane & 15;
  const unsigned short* qp = qkv + (size_t)r * C3_ + (u << 4);
  float qv[16];
  unpack8(*(const uint4*)qp, qv);
  unpack8(*(const uint4*)(qp + 8), qv + 8);
  float sc[5];
  #pragma unroll
  for (int rnd = 0; rnd < 5; rnd++) {
    int j = rnd * 4 + g;
    int jj = t - 16 + j;
    bool valid = (j <= 16) && (jj >= 0);
    float d = 0.f;
    if (valid) {
      const unsigned short* kp = qkv + (size_t)(r - 16 + j) * C3_ + 256 + (u << 4);
      float kv[16];
      unpack8(*(const uint4*)kp, kv);
      unpack8(*(const uint4*)(kp + 8), kv + 8);
      #pragma unroll
      for (int c = 0; c < 16; c++) d += qv[c] * kv[c];
    }
    d += __shfl_xor(d, 1); d += __shfl_xor(d, 2);
    d += __shfl_xor(d, 4); d += __shfl_xor(d, 8);
    sc[rnd] = valid ? d * 0.0625f : -1e30f;
  }
  float m = fmaxf(fmaxf(fmaxf(sc[0], sc[1]), fmaxf(sc[2], sc[3])), sc[4]);
  m = fmaxf(m, __shfl_xor(m, 16));
  m = fmaxf(m, __shfl_xor(m, 32));
  if (t > 16) m = fmaxf(m, 0.0f);
  float ev[5], Zp = 0.f;
  #pragma unroll
  for (int rnd = 0; rnd < 5; rnd++) {
    ev[rnd] = (sc[rnd] > -1e29f) ? __expf(sc[rnd] - m) : 0.f;
    Zp += ev[rnd];
  }
  Zp += __shfl_xor(Zp, 16);
  Zp += __shfl_xor(Zp, 32);
  float e0v = 0.f;
  if (t > 16) { e0v = __expf(-m); Zp += e0v * (float)(t - 16); }
  float vp[16];
  #pragma unroll
  for (int c = 0; c < 16; c++) vp[c] = 0.f;
  #pragma unroll
  for (int rnd = 0; rnd < 5; rnd++) {
    if (ev[rnd] != 0.f) {
      int j = rnd * 4 + g;
      const unsigned short* vpp = qkv + (size_t)(r - 16 + j) * C3_ + 512 + (u << 4);
      float vv[16];
      unpack8(*(const uint4*)vpp, vv);
      unpack8(*(const uint4*)(vpp + 8), vv + 8);
      #pragma unroll
      for (int c = 0; c < 16; c++) vp[c] += ev[rnd] * vv[c];
    }
  }
  #pragma unroll
  for (int c = 0; c < 16; c++) {
    vp[c] += __shfl_xor(vp[c], 16);
    vp[c] += __shfl_xor(vp[c], 32);
  }
  if (g == 0) {
    if (t > 16) {
      const unsigned short* pp = Pb + (size_t)(r - 17) * C_ + (u << 4);
      float pv[16];
      unpack8(*(const uint4*)pp, pv);
      unpack8(*(const uint4*)(pp + 8), pv + 8);
      #pragma unroll
      for (int c = 0; c < 16; c++) vp[c] += e0v * pv[c];
    }
    float inv = 1.0f / Zp;
    const float* gp = gate + (u << 4);
    unsigned int ow[8];
    #pragma unroll
    for (int i = 0; i < 8; i++) {
      unsigned short lo = f2b(vp[2*i] * inv * gp[2*i]);
      unsigned short hi = f2b(vp[2*i+1] * inv * gp[2*i+1]);
      ow[i] = (unsigned int)lo | ((unsigned int)hi << 16);
    }
    uint4 s0 = {ow[0], ow[1], ow[2], ow[3]};
    uint4 s1 = {ow[4], ow[5], ow[6], ow[7]};
    *(uint4*)(aout + (size_t)r * C_ + (u << 4)) = s0;
    *(uint4*)(aout + (size_t)r * C_ + (u << 4) + 8) = s1;
  }
}

// ---------------- 128x128 MFMA GEMM, operand-swapped, swizzled staging ------------------
// EPI 0: outb = bf16(acc + bias)                              (qkv)
// EPI 1: x1 = acc + bias + resid                              (proj)
template<int EPI>
__global__ __launch_bounds__(256) void gemm128(
    const unsigned short* __restrict__ A, const unsigned short* __restrict__ Bt,
    const float* __restrict__ bias, int K, int ldOut,
    const float* __restrict__ resid, float* __restrict__ outf,
    unsigned short* __restrict__ outb) {
  __shared__ __align__(16) unsigned short As[128 * 64];
  __shared__ __align__(16) unsigned short Bs[128 * 64];
  const int tid = threadIdx.x;
  const int wave = tid >> 6, lane = tid & 63;
  const int mBlk = blockIdx.x * 128, nBlk = blockIdx.y * 128;
  const int wm = (wave >> 1) * 64, wn = (wave & 1) * 64;
  const int lm = lane & 15, lk = (lane >> 4) * 8;
  floatx4 acc[4][4];
  #pragma unroll
  for (int i = 0; i < 4; i++)
    #pragma unroll
    for (int j = 0; j < 4; j++) acc[i][j] = (floatx4){0.f, 0.f, 0.f, 0.f};

  for (int kt = 0; kt < K; kt += 64) {
    __syncthreads();
    #pragma unroll
    for (int i = 0; i < 4; i++) {
      int seg = i * 256 + tid;          // 16B segment index
      int row = seg >> 3, g = seg & 7;
      int gc = (g ^ (row & 7)) << 3;    // XOR-swizzle the GLOBAL column (LDS stays linear)
      gl_lds16(A + (size_t)(mBlk + row) * K + kt + gc, &As[seg * 8]);
      gl_lds16(Bt + (size_t)(nBlk + row) * K + kt + gc, &Bs[seg * 8]);
    }
    __syncthreads();
    #pragma unroll
    for (int kk = 0; kk < 64; kk += 32) {
      short8 mf[4], nf[4];
      #pragma unroll
      for (int j = 0; j < 4; j++) {
        int row = wm + j * 16 + lm;
        mf[j] = *(const short8*)&As[row * 64 + ((((kk + lk) >> 3) ^ (row & 7)) << 3)];
      }
      #pragma unroll
      for (int i = 0; i < 4; i++) {
        int row = wn + i * 16 + lm;
        nf[i] = *(const short8*)&Bs[row * 64 + ((((kk + lk) >> 3) ^ (row & 7)) << 3)];
      }
      #pragma unroll
      for (int i = 0; i < 4; i++)
        #pragma unroll
        for (int j = 0; j < 4; j++)
          acc[i][j] = __builtin_amdgcn_mfma_f32_16x16x32_bf16(nf[i], mf[j], acc[i][j], 0, 0, 0);
    }
  }
  const int lc = lane & 15, quad = lane >> 4, q4 = quad * 4;
  #pragma unroll
  for (int i = 0; i < 4; i++) {
    int n0 = nBlk + wn + i * 16 + q4;
    float4 bs = *(const float4*)&bias[n0];
    #pragma unroll
    for (int j = 0; j < 4; j++) {
      int m = mBlk + wm + j * 16 + lc;
      float v0 = acc[i][j][0] + bs.x, v1 = acc[i][j][1] + bs.y;
      float v2 = acc[i][j][2] + bs.z, v3 = acc[i][j][3] + bs.w;
      if (EPI == 0) {
        ushort4 o = {f2b(v0), f2b(v1), f2b(v2), f2b(v3)};
        *(ushort4*)&outb[(size_t)m * ldOut + n0] = o;
      } else {
        size_t idx = (size_t)m * ldOut + n0;
        float4 r = *(const float4*)&resid[idx];
        float4 o = {v0 + r.x, v1 + r.y, v2 + r.z, v3 + r.w};
        *(float4*)&outf[idx] = o;
      }
    }
  }
}

// ---------------- fused MoE, producer/consumer wave split, 1 barrier/iter ---------------
// 512 threads: waves 0-3 = up (h2@w1 + gelu + fp8 -> Hs), waves 4-7 = down (Hs@w2 -> dacc).
// Down lags up by one chunk (Hs double-buffered).
// Per iter: barrier -> stage-issue(c+1) -> compute(c) -> vmcnt(0).
// Safety: the top barrier bounds wave skew to one iteration, so restaged buffers
// (W1s[wb^1], W2s[wb]) were last read in compute(c-1), finished by ALL waves before the
// barrier.  Each wave drains its OWN stage DMA with vmcnt(0) BEFORE the next barrier,
// so after the barrier every wave's chunk-(c+1) loads are landed and visible -> the
// second barrier of the R2/R5 schedule is redundant (64 barrier syncs removed).
// setprio(1) wraps the MFMA clusters (T5: pays with producer/consumer role diversity).
__global__ __launch_bounds__(512, 2) void moe_fused(
    const unsigned short* __restrict__ h2,   // [M,256] bf16
    const unsigned short* __restrict__ w1t,  // [4096,256] bf16
    const float* __restrict__ b1,            // [4096] flat
    const unsigned char* __restrict__ w2b,   // [64][256][64] fp8 (x256, seg-swizzled)
    const float* __restrict__ b2,            // [4][256]
    const float* __restrict__ gates,         // [M,4]
    const float* __restrict__ x1,            // [M,256]
    float* __restrict__ out) {
  __shared__ __align__(16) unsigned short W1s[2][64 * 256];    // 64 KB
  __shared__ __align__(16) unsigned char  W2s[2][256 * 64];    // 32 KB
  __shared__ __align__(16) unsigned char  Hs[2][64 * 64];      // 8 KB
  __shared__ __align__(16) float          B1s[2][64];          // 512 B
  const int tid = threadIdx.x;
  const int wave = tid >> 6, lane = tid & 63;
  const int lm = lane & 15, quad = lane >> 4;
  const int mb = blockIdx.x * 64;
  const bool isUp = wave < 4;
  const int uw = wave & 3;
  const int wmu = (uw >> 1) * 32;     // up-tile m offset
  const int whu = (uw & 1) * 32;      // up-tile h offset
  const int wc  = uw * 64;            // down-tile c offset

  // stage W1 chunk c + b1 slice into buffer buf: 5 vmem instrs/wave
  auto stageW1 = [&](int c, int buf) {
    const unsigned short* ws = w1t + (size_t)c * 64 * C_;
    #pragma unroll
    for (int t = 0; t < 4; t++) {
      int seg = t * 512 + tid;
      int row = seg >> 5, g = seg & 31;
      int gp = (g & 24) | ((g & 7) ^ (row & 7));
      gl_lds16(ws + (size_t)row * C_ + gp * 8, &W1s[buf][seg * 8]);
    }
    if (lane < 16)
      gl_lds16(b1 + (size_t)c * 64 + lane * 4, &B1s[buf][0]);
  };
  // stage W2 chunk c into buffer buf: 2 vmem instrs/wave (pre-blocked linear 16 KB)
  auto stageW2 = [&](int c, int buf) {
    const unsigned char* vs = w2b + (size_t)c * 256 * 64;
    #pragma unroll
    for (int t = 0; t < 2; t++) {
      int seg = t * 512 + tid;
      gl_lds16(vs + (size_t)seg * 16, &W2s[buf][seg * 16]);
    }
  };

  stageW1(0, 0);

  // A-fragments -> registers (up waves): h2 rows [mb+wmu, +32), read once, reused 64 chunks
  short8 af[8][2];
  float4 ga[2];
  if (isUp) {
    #pragma unroll
    for (int kk = 0; kk < 8; kk++) {
      int kc = kk * 4 + quad;
      #pragma unroll
      for (int j = 0; j < 2; j++) {
        int row = mb + wmu + j * 16 + lm;
        af[kk][j] = *(const short8*)(h2 + (size_t)row * C_ + kc * 8);
      }
    }
    #pragma unroll
    for (int j = 0; j < 2; j++)
      ga[j] = *(const float4*)(gates + (size_t)(mb + wmu + j * 16 + lm) * 4);
  }

  floatx4 dacc[4][4];   // [i = c-frag][j = m-frag], down waves only
  #pragma unroll
  for (int i = 0; i < 4; i++)
    #pragma unroll
    for (int j = 0; j < 4; j++) dacc[i][j] = (floatx4){0.f, 0.f, 0.f, 0.f};

  // prologue: own chunk-0 stage (and af/ga loads) landed before first barrier
  asm volatile("s_waitcnt vmcnt(0)" ::: "memory");

  for (int c = 0; c < 64; c++) {
    const int wb = c & 1;
    // single barrier: everyone's prev-iter stages landed (own vmcnt(0) before arrival)
    // and everyone finished compute(c-1) -> restage + read both safe
    __builtin_amdgcn_s_barrier();
    __builtin_amdgcn_sched_barrier(0);
    // stage issue first: DMA flight overlaps the whole compute phase below
    stageW1((c + 1) & 63, wb ^ 1);     // W1/b1 for chunk c+1 (wrap harmless)
    stageW2(c, wb);                    // W2 for chunk c (consumed next iter)

    if (isUp) {
      // ---- up-GEMM chunk c: uacc = h2[32m] x w1[32h], K=256
      floatx4 uacc[2][2];
      #pragma unroll
      for (int i = 0; i < 2; i++)
        #pragma unroll
        for (int j = 0; j < 2; j++) uacc[i][j] = (floatx4){0.f, 0.f, 0.f, 0.f};
      __builtin_amdgcn_s_setprio(1);
      #pragma unroll
      for (int kk = 0; kk < 8; kk++) {
        int kc = kk * 4 + quad;
        short8 nf[2];
        #pragma unroll
        for (int i = 0; i < 2; i++) {
          int row = whu + i * 16 + lm;
          nf[i] = *(const short8*)&W1s[wb][row * 256 + ((kc ^ (row & 7)) << 3)];
        }
        #pragma unroll
        for (int i = 0; i < 2; i++)
          #pragma unroll
          for (int j = 0; j < 2; j++)
            uacc[i][j] = __builtin_amdgcn_mfma_f32_16x16x32_bf16(nf[i], af[kk][j], uacc[i][j], 0, 0, 0);
      }
      __builtin_amdgcn_s_setprio(0);
      // ---- gelu + gate + fp8 -> Hs[wb], XOR-swizzled 8B granules
      int e = c >> 4;
      float gs0 = 64.0f * sel4(ga[0], e);
      float gs1 = 64.0f * sel4(ga[1], e);
      #pragma unroll
      for (int i = 0; i < 2; i++) {
        float4 bb = *(const float4*)&B1s[wb][whu + i * 16 + quad * 4];
        #pragma unroll
        for (int j = 0; j < 2; j++) {
          float gs = j ? gs1 : gs0;
          unsigned int w = pk_fp8x4(gs * gelu_s(uacc[i][j][0] + bb.x),
                                    gs * gelu_s(uacc[i][j][1] + bb.y),
                                    gs * gelu_s(uacc[i][j][2] + bb.z),
                                    gs * gelu_s(uacc[i][j][3] + bb.w));
          int m = wmu + j * 16 + lm;
          int hh = whu + i * 16 + quad * 4;
          *(unsigned int*)&Hs[wb][m * 64 + ((((hh >> 3) ^ (m & 7)) << 3) | (hh & 7))] = w;
        }
      }
      asm volatile("s_waitcnt lgkmcnt(0)" ::: "memory");   // Hs writes landed before barrier
    } else if (c > 0) {
      // ---- down-GEMM chunk c-1: dacc += hid8[64m x 64k] x w2[64c x 64k] (fp8)
      const int pb = wb ^ 1;
      __builtin_amdgcn_s_setprio(1);
      #pragma unroll
      for (int kk = 0; kk < 2; kk++) {
        long mfh[4], nfw[4];
        #pragma unroll
        for (int j = 0; j < 4; j++) {
          int m = j * 16 + lm;
          int g8 = quad + 4 * kk;
          mfh[j] = *(const long*)&Hs[pb][m * 64 + ((g8 ^ (m & 7)) << 3)];
        }
        #pragma unroll
        for (int i = 0; i < 4; i++) {
          int cr = wc + i * 16 + lm;
          int sl = ((quad >> 1) + 2 * kk) ^ ((cr >> 2) & 3);
          nfw[i] = *(const long*)&W2s[pb][cr * 64 + (sl << 4) + ((quad & 1) << 3)];
        }
        #pragma unroll
        for (int i = 0; i < 4; i++)
          #pragma unroll
          for (int j = 0; j < 4; j++)
            dacc[i][j] = __builtin_amdgcn_mfma_f32_16x16x32_fp8_fp8(nfw[i], mfh[j], dacc[i][j], 0, 0, 0);
      }
      __builtin_amdgcn_s_setprio(0);
    }
    // own stage loads landed before announcing arrival at the next barrier
    asm volatile("s_waitcnt vmcnt(0)" ::: "memory");
  }

  // ---- drain: final down step for chunk 63 (Hs[1], W2s[1]), then epilogue
  __builtin_amdgcn_s_barrier();
  __builtin_amdgcn_sched_barrier(0);
  if (!isUp) {
    #pragma unroll
    for (int kk = 0; kk < 2; kk++) {
      long mfh[4], nfw[4];
      #pragma unroll
      for (int j = 0; j < 4; j++) {
        int m = j * 16 + lm;
        int g8 = quad + 4 * kk;
        mfh[j] = *(const long*)&Hs[1][m * 64 + ((g8 ^ (m & 7)) << 3)];
      }
      #pragma unroll
      for (int i = 0; i < 4; i++) {
        int cr = wc + i * 16 + lm;
        int sl = ((quad >> 1) + 2 * kk) ^ ((cr >> 2) & 3);
        nfw[i] = *(const long*)&W2s[1][cr * 64 + (sl << 4) + ((quad & 1) << 3)];
      }
      #pragma unroll
      for (int i = 0; i < 4; i++)
        #pragma unroll
        for (int j = 0; j < 4; j++)
          dacc[i][j] = __builtin_amdgcn_mfma_f32_16x16x32_fp8_fp8(nfw[i], mfh[j], dacc[i][j], 0, 0, 0);
    }
    // ---- epilogue: out = dacc/2^14 + x1 + sum_e gate_e * b2_e
    const float sc = 1.0f / 16384.0f;
    const int q4 = quad * 4;
    #pragma unroll
    for (int j = 0; j < 4; j++) {
      int m = mb + j * 16 + lm;
      float4 g4 = *(const float4*)(gates + (size_t)m * 4);
      #pragma unroll
      for (int i = 0; i < 4; i++) {
        int n0 = wc + i * 16 + q4;
        float4 bA = *(const float4*)&b2[0 * C_ + n0];
        float4 bB = *(const float4*)&b2[1 * C_ + n0];
        float4 bC = *(const float4*)&b2[2 * C_ + n0];
        float4 bD = *(const float4*)&b2[3 * C_ + n0];
        size_t idx = (size_t)m * C_ + n0;
        float4 r = *(const float4*)&x1[idx];
        float4 o;
        o.x = dacc[i][j][0]*sc + r.x + g4.x*bA.x + g4.y*bB.x + g4.z*bC.x + g4.w*bD.x;
        o.y = dacc[i][j][1]*sc + r.y + g4.x*bA.y + g4.y*bB.y + g4.z*bC.y + g4.w*bD.y;
        o.z = dacc[i][j][2]*sc + r.z + g4.x*bA.z + g4.y*bB.z + g4.z*bC.z + g4.w*bD.z;
        o.w = dacc[i][j][3]*sc + r.w + g4.x*bA.w + g4.y*bB.w + g4.z*bC.w + g4.w*bD.w;
        *(float4*)&out[idx] = o;
      }
    }
  }
}

extern "C" void kernel_launch(void* const* d_in, const int* in_sizes, int n_in,
                              void* d_out, int out_size, void* d_ws, size_t ws_size,
                              hipStream_t stream) {
  const float* x       = (const float*)d_in[0];
  const float* ln1_g   = (const float*)d_in[1];
  const float* ln1_b   = (const float*)d_in[2];
  const float* qkv_w   = (const float*)d_in[3];
  const float* qkv_b   = (const float*)d_in[4];
  const float* proj_w  = (const float*)d_in[5];
  const float* proj_b  = (const float*)d_in[6];
  const float* attn_g  = (const float*)d_in[7];
  const float* ln2_g   = (const float*)d_in[8];
  const float* ln2_b   = (const float*)d_in[9];
  const float* gat_w   = (const float*)d_in[10];
  const float* gat_b   = (const float*)d_in[11];
  const float* e_w1    = (const float*)d_in[12];
  const float* e_b1    = (const float*)d_in[13];
  const float* e_w2    = (const float*)d_in[14];
  const float* e_b2    = (const float*)d_in[15];
  float* out = (float*)d_out;

  char* p = (char*)d_ws;
  unsigned short* h    = (unsigned short*)p; p += (size_t)M_ * C_ * 2;      // 8 MB
  unsigned short* qkv  = (unsigned short*)p; p += (size_t)M_ * C3_ * 2;     // 24 MB
  unsigned short* Pb   = (unsigned short*)p; p += (size_t)M_ * C_ * 2;      // 8 MB
  unsigned short* aout = (unsigned short*)p; p += (size_t)M_ * C_ * 2;      // 8 MB
  float*          x1   = (float*)p;          p += (size_t)M_ * C_ * 4;      // 16 MB
  unsigned short* h2   = (unsigned short*)p; p += (size_t)M_ * C_ * 2;      // 8 MB
  float*          gts  = (float*)p;          p += (size_t)M_ * E_ * 4;      // 256 KB
  float*          S    = (float*)p;          p += (size_t)B_ * NCH_ * C_ * 4;
  unsigned short* wq   = (unsigned short*)p; p += (size_t)C3_ * C_ * 2;
  unsigned short* wp   = (unsigned short*)p; p += (size_t)C_ * C_ * 2;
  unsigned short* w1t  = (unsigned short*)p; p += (size_t)KH_ * C_ * 2;     // 2 MB [4096,256]
  unsigned char*  w2f8 = (unsigned char*)p;  p += (size_t)C_ * KH_;         // 1 MB blocked

  dim3 t32x8(32, 8);
  transpose_cvt<<<dim3(C3_/32, C_/32, 1), t32x8, 0, stream>>>(qkv_w, wq, C_, C3_, C_, 0);
  transpose_cvt<<<dim3(C_/32, C_/32, 1),  t32x8, 0, stream>>>(proj_w, wp, C_, C_, C_, 0);
  // w1t[e*1024 + hrow][c]  (flat [4096, 256]) bf16
  transpose_cvt<<<dim3(H_/32, C_/32, E_), t32x8, 0, stream>>>(e_w1, w1t, C_, H_, C_, (size_t)H_ * C_);
  // w2 -> fp8 x256, blocked [64 chunks][c][64] with (c>>2) seg swizzle
  transpose_w2_fp8<<<dim3(H_/32, C_/32, E_), t32x8, 0, stream>>>(e_w2, w2f8);

  ln1_kernel<<<M_, 256, 0, stream>>>(x, ln1_g, ln1_b, h);
  gemm128<0><<<dim3(M_/128, C3_/128), 256, 0, stream>>>(h, wq, qkv_b, C_, C3_,
      nullptr, nullptr, qkv);
  scan1_kernel<<<B_*NCH_, 256, 0, stream>>>(qkv, S);
  scan2_kernel<<<B_, 256, 0, stream>>>(S);
  scan3_kernel<<<B_*NCH_, 256, 0, stream>>>(qkv, S, Pb);
  attn_kernel<<<M_/4, 256, 0, stream>>>(qkv, Pb, attn_g, aout);
  // x1 = x + aout @ proj_w + proj_b
  gemm128<1><<<dim3(M_/128, C_/128), 256, 0, stream>>>(aout, wp, proj_b, C_, C_,
      x, x1, nullptr);
  ln2_gates_kernel<<<M_, 256, 0, stream>>>(x1, ln2_g, ln2_b, gat_w, gat_b, h2, gts);
  // fused MoE: producer waves (up+gelu+fp8) || consumer waves (down), 1 barrier/iter
  moe_fused<<<M_/64, 512, 0, stream>>>(h2, w1t, e_b1, w2f8, e_b2, gts, x1, out);
}